// Round 16
// baseline (207.933 us; speedup 1.0000x reference)
//
#include <hip/hip_runtime.h>
#include <math.h>

#define BB 4
#define LL 512000
#define NF 512
#define TT 3997
#define FF 257
#define FPW 2
#define TWO_PI 6.28318530717958647692f
#define PI_F 3.14159265358979323846f
// fl32(2*pi) — what the f32 numpy port uses building theta and window args:
#define TPI_F32 6.28318548202514648f

static const size_t SPEC_N = (size_t)BB * FF * TT;   // 4,108,916
static const size_t BNT    = (size_t)BB * NF * TT;   // 8,185,856
// layout B (confirmed r11): spec | stft real-part (BNT) | real | imag | phase

#define AB_IM  3.0e-5f
#define RE_MAX 1.0e-4f
#define Z2_MIN 1.0e-8f

__device__ __forceinline__ float neg_zero() { return __uint_as_float(0x80000000u); }

// Barriered ops: exactly one IEEE-RN rounding each (stops -ffp-contract=fast
// from fusing where numpy has separate ops).
__device__ __forceinline__ float mulrn(float a, float b) { float t = a * b; asm("" : "+v"(t)); return t; }
__device__ __forceinline__ float addrn(float a, float b) { float t = a + b; asm("" : "+v"(t)); return t; }
// Single-rounded fused a*b+c (npyv_muladd on AVX512 = FMA):
__device__ __forceinline__ float fmarn(float a, float b, float c) { float t = fmaf(a, b, c); asm("" : "+v"(t)); return t; }

// np f32 theta: fl32(fl32(2pi)*k)/512  (k = f*n < 2^24 exact; /512 exact)
__device__ __forceinline__ float theta32(int k) {
    return mulrn(TPI_F32, (float)k) / 512.0f;
}

__device__ __forceinline__ int bitrev6(int l) { return (int)(__brev((unsigned)l) >> 26); }

// exrow swizzle: XOR bits5-7 onto bits0-2 — makes the 8b+a staging writes
// 2-way (free) and npyv-dot reads conflict-free. Bijective.
__device__ __forceinline__ int exr_idx(int n) { return n ^ ((n >> 5) & 7); }

// Wave-private LDS sync (rule #18: sched_barrier after inline-asm waitcnt)
#define WAVE_SYNC() do { asm volatile("s_waitcnt lgkmcnt(0)" ::: "memory"); \
                         __builtin_amdgcn_sched_barrier(0); } while (0)

// _mm512_reduce_add_ps tree over 16 partials held by lanes base..base+15
__device__ __forceinline__ float hsum16(float s, int base) {
    float q[4];
#pragma unroll
    for (int k = 0; k < 4; ++k) {
        float a = addrn(__shfl(s, base + k),     __shfl(s, base + k + 8));
        float b = addrn(__shfl(s, base + k + 4), __shfl(s, base + k + 12));
        q[k] = addrn(a, b);
    }
    return addrn(addrn(q[0], q[2]), addrn(q[1], q[3]));
}

// ---------------------------------------------------------------------------
__global__ void dstft_sin256(float* __restrict__ s256g)
{
    int n = threadIdx.x;   // 512 threads
    s256g[n] = (float)sin((double)theta32(256 * n));
}

// ---------------------------------------------------------------------------
// Fast-path per-slot window weights for n = 8*rb + a (a=0..7).
__device__ __forceinline__ void fast_weights(
    float frac, float wl, float wpow, bool dopow, int rb, float* wwf)
{
    float shift = (wl - 511.0f) * 0.5f;
    float lower = floorf((511.0f - wl) * 0.5f);
    float upper = ceilf ((511.0f + wl) * 0.5f);
    float psum = 0.0f;
#pragma unroll
    for (int a = 0; a < 8; ++a) {
        int n = 8 * rb + a;
        float base = (float)n - frac;
        float w = 0.0f;
        if (base > lower && base < upper)
            w = 0.5f - 0.5f * cosf(TWO_PI * (base + shift) / wl);
        wwf[a] = w;
        psum += w;
    }
#pragma unroll
    for (int off = 32; off > 0; off >>= 1) psum += __shfl_xor(psum, off);
    float inv = 1.0f / psum;
#pragma unroll
    for (int a = 0; a < 8; ++a) {
        float w = wwf[a] * inv;
        if (dopow) w = powf(w, wpow);
        wwf[a] = w;
    }
}

// ---------------------------------------------------------------------------
// One frame: loads + FFT (8x64, f = lane + 64*j) + nyq + gold patches.
// S[8] out; nyq out. exrow is wave-private LDS (NF floats, swizzled).
__device__ __forceinline__ void compute_frame(
    const float* __restrict__ xb, int i0, float frac,
    float wl, float wpow, bool dopow, const float* wwf,
    const float* __restrict__ s256f, float* __restrict__ exrow,
    const float* stc, const float* sts, const float* wac, const float* was,
    int lane, int rb, bool active, float2* S, float* nyq_out)
{
    // ---- loads: 8 contiguous floats at i0 + 8*rb
    int nb = i0 + 8 * rb;
    float xr[8];
    if (active && nb >= 0 && nb + 7 < LL && ((i0 & 3) == 0)) {
        float4 p0 = *reinterpret_cast<const float4*>(xb + nb);
        float4 p1 = *reinterpret_cast<const float4*>(xb + nb + 4);
        xr[0] = p0.x; xr[1] = p0.y; xr[2] = p0.z; xr[3] = p0.w;
        xr[4] = p1.x; xr[5] = p1.y; xr[6] = p1.z; xr[7] = p1.w;
    } else {
#pragma unroll
        for (int a = 0; a < 8; ++a) {
            int idx = nb + a;
            xr[a] = (active && idx >= 0 && idx < LL) ? xb[idx] : 0.0f;
        }
    }
    float tap[8];
#pragma unroll
    for (int a = 0; a < 8; ++a) {
        tap[a] = xr[a] * wwf[a];
        exrow[exr_idx(8 * rb + a)] = tap[a];
    }

    // ---- 4 packed real-pair 64-pt DIT DFTs across lanes
    float2 z[4];
#pragma unroll
    for (int c = 0; c < 4; ++c) z[c] = make_float2(tap[2 * c], tap[2 * c + 1]);
    // stage h=1 (w=1)
#pragma unroll
    for (int c = 0; c < 4; ++c) {
        float px = __shfl_xor(z[c].x, 1), py = __shfl_xor(z[c].y, 1);
        if (lane & 1) { z[c].x = px - z[c].x; z[c].y = py - z[c].y; }
        else          { z[c].x += px;         z[c].y += py; }
    }
    // stages h=2..32
#pragma unroll
    for (int s = 1; s < 6; ++s) {
        int h = 1 << s;
        float wc = stc[s - 1], ws = sts[s - 1];
#pragma unroll
        for (int c = 0; c < 4; ++c) {
            float px = __shfl_xor(z[c].x, h), py = __shfl_xor(z[c].y, h);
            if (lane & h) {
                float wx = wc * z[c].x - ws * z[c].y;
                float wy = wc * z[c].y + ws * z[c].x;
                z[c].x = px - wx; z[c].y = py - wy;
            } else {
                float wx = wc * px - ws * py;
                float wy = wc * py + ws * px;
                z[c].x += wx; z[c].y += wy;
            }
        }
    }
    // ---- hermitian unpack: B[2c] + i*B[2c+1] = Z_c ; Zr = Z_c[(64-k)%64]
    float2 Bv[8];
    {
        int srcl = (64 - lane) & 63;
#pragma unroll
        for (int c = 0; c < 4; ++c) {
            float rx = __shfl(z[c].x, srcl), ry = __shfl(z[c].y, srcl);
            Bv[2 * c]     = make_float2(0.5f * (z[c].x + rx), 0.5f * (z[c].y - ry));
            Bv[2 * c + 1] = make_float2(0.5f * (z[c].y + ry), -0.5f * (z[c].x - rx));
        }
    }
    // ---- twiddle W512^{a*lane}
#pragma unroll
    for (int a = 1; a < 8; ++a) {
        float wc = wac[a - 1], ws = was[a - 1];
        float vx = Bv[a].x, vy = Bv[a].y;
        Bv[a] = make_float2(vx * wc - vy * ws, vx * ws + vy * wc);
    }
    // ---- 8-pt complex DFT over slots: S[j] for f = lane + 64*j
    {
        const float Cq = 0.70710678118654752440f;
        float ex0 = Bv[0].x + Bv[4].x, ey0 = Bv[0].y + Bv[4].y;
        float dx0 = Bv[0].x - Bv[4].x, dy0 = Bv[0].y - Bv[4].y;
        float ex1 = Bv[2].x + Bv[6].x, ey1 = Bv[2].y + Bv[6].y;
        float dx1 = Bv[2].x - Bv[6].x, dy1 = Bv[2].y - Bv[6].y;
        float2 E0 = make_float2(ex0 + ex1, ey0 + ey1);
        float2 E2 = make_float2(ex0 - ex1, ey0 - ey1);
        float2 E1 = make_float2(dx0 + dy1, dy0 - dx1);
        float2 E3 = make_float2(dx0 - dy1, dy0 + dx1);
        float ox0 = Bv[1].x + Bv[5].x, oy0 = Bv[1].y + Bv[5].y;
        float qx0 = Bv[1].x - Bv[5].x, qy0 = Bv[1].y - Bv[5].y;
        float ox1 = Bv[3].x + Bv[7].x, oy1 = Bv[3].y + Bv[7].y;
        float qx1 = Bv[3].x - Bv[7].x, qy1 = Bv[3].y - Bv[7].y;
        float2 O0 = make_float2(ox0 + ox1, oy0 + oy1);
        float2 O2 = make_float2(ox0 - ox1, oy0 - oy1);
        float2 O1 = make_float2(qx0 + qy1, qy0 - qx1);
        float2 O3 = make_float2(qx0 - qy1, qy0 + qx1);
        float2 T0 = O0;
        float2 T1 = make_float2(Cq * (O1.x + O1.y), Cq * (O1.y - O1.x));
        float2 T2 = make_float2(O2.y, -O2.x);
        float2 T3 = make_float2(Cq * (O3.y - O3.x), -Cq * (O3.x + O3.y));
        S[0] = make_float2(E0.x + T0.x, E0.y + T0.y);
        S[4] = make_float2(E0.x - T0.x, E0.y - T0.y);
        S[1] = make_float2(E1.x + T1.x, E1.y + T1.y);
        S[5] = make_float2(E1.x - T1.x, E1.y - T1.y);
        S[2] = make_float2(E2.x + T2.x, E2.y + T2.y);
        S[6] = make_float2(E2.x - T2.x, E2.y - T2.y);
        S[3] = make_float2(E3.x + T3.x, E3.y + T3.y);
        S[7] = make_float2(E3.x - T3.x, E3.y - T3.y);
    }
    WAVE_SYNC();   // exrow tap writes landed

    // ---- imag[256] = -(npyv forward dot of taps with s256f) — always
    {
        float s = 0.0f;
        if (lane < 16) {
#pragma unroll 1
            for (int i = 0; i < 8; ++i) {
                int base = 64 * i + lane;
                s = fmarn(exrow[exr_idx(base +  0)], s256f[base +  0], s);
                s = fmarn(exrow[exr_idx(base + 16)], s256f[base + 16], s);
                s = fmarn(exrow[exr_idx(base + 32)], s256f[base + 32], s);
                s = fmarn(exrow[exr_idx(base + 48)], s256f[base + 48], s);
            }
        }
        *nyq_out = -hsum16(s, 0);
    }

    // ---- flag scan: f = lane + 64*j (phase bins f<=256 only)
    unsigned long long flags[5];
    unsigned long long anyf = 0ULL;
#pragma unroll
    for (int j = 0; j < 5; ++j) {
        float2 vv = S[j];
        bool flg = false;
        if (active) {
            if (j == 0 && lane == 0)      flg = fabsf(vv.x) < RE_MAX;   // f=0
            else if (j == 4)              flg = (lane == 0) && (fabsf(vv.x) < RE_MAX); // f=256
            else                          flg = (fabsf(vv.y) < AB_IM && vv.x < RE_MAX) ||
                                                (vv.x * vv.x + vv.y * vv.y < Z2_MIN);
        }
        flags[j] = __ballot(flg);
        anyf |= flags[j];
    }

    if (anyf) {
        // ---- gold window (f32 ops, f64-rounded cos) — R13-verified sequence
        float g_shift = mulrn(addrn(wl - 512.0f, 1.0f), 0.5f);
        float g_lower = floorf(mulrn(511.0f - wl, 0.5f));
        float g_upper = ceilf (mulrn(511.0f + wl, 0.5f));
        float gw[8];
#pragma unroll
        for (int a = 0; a < 8; ++a) {
            int n = 8 * rb + a;
            float base = (float)n - frac;
            float w = 0.0f;
            if (base > g_lower && base < g_upper) {
                float arg = mulrn(TPI_F32, addrn(base, g_shift)) / wl;
                w = 0.5f - mulrn(0.5f, (float)cos((double)arg));
            }
            gw[a] = w;
            exrow[exr_idx(n)] = w;
        }
        WAVE_SYNC();
        // psum: np.sum(axis=0) = strictly sequential over n
        float ps = 0.0f;
        if (lane == 0) {
#pragma unroll 1
            for (int n = 0; n < NF; ++n) ps = addrn(ps, exrow[exr_idx(n)]);
        }
        ps = __shfl(ps, 0);
#pragma unroll
        for (int a = 0; a < 8; ++a) {
            int n = 8 * rb + a;
            float w = gw[a] / ps;                  // np: tap / sum (f32 div)
            if (dopow) w = powf(w, wpow);
            exrow[exr_idx(n)] = mulrn(xr[a], w);   // gold tapered
        }
        WAVE_SYNC();

#pragma unroll
        for (int j = 0; j < 5; ++j) {
            unsigned long long m = flags[j];
            while (m) {
                int src = (int)(__ffsll(m) - 1);
                m &= m - 1;
                int ff = src + 64 * j;
                // lanes 0-15: sin partials; 16-31: cos; FORWARD npyv chain
                float s = 0.0f;
                if (lane < 32) {
                    int L = lane & 15;
                    bool isCos = lane >= 16;
#pragma unroll 1
                    for (int i = 0; i < 8; ++i) {
                        int base = 64 * i + L;
#pragma unroll
                        for (int Bq = 0; Bq < 4; ++Bq) {
                            int n = base + 16 * Bq;
                            double sv, cv;
                            sincos((double)theta32(ff * n), &sv, &cv);
                            s = fmarn(exrow[exr_idx(n)], isCos ? (float)cv : (float)sv, s);
                        }
                    }
                }
                float im = hsum16(s, 0);
                float re = hsum16(s, 16);
                if (lane == src) S[j] = make_float2(re, -im);
            }
        }
        // gold nyq from gold taps
        {
            float s = 0.0f;
            if (lane < 16) {
#pragma unroll 1
                for (int i = 0; i < 8; ++i) {
                    int base = 64 * i + lane;
                    s = fmarn(exrow[exr_idx(base +  0)], s256f[base +  0], s);
                    s = fmarn(exrow[exr_idx(base + 16)], s256f[base + 16], s);
                    s = fmarn(exrow[exr_idx(base + 32)], s256f[base + 32], s);
                    s = fmarn(exrow[exr_idx(base + 48)], s256f[base + 48], s);
                }
            }
            *nyq_out = -hsum16(s, 0);
        }
    }
    WAVE_SYNC();
}

// ---------------------------------------------------------------------------
__global__ __launch_bounds__(256) void dstft_fft_kernel(
    const float* __restrict__ x,
    const float* __restrict__ p_stride,
    const float* __restrict__ p_winlen,
    const float* __restrict__ p_winpow,
    const float* __restrict__ s256g,
    float2* __restrict__ scr, size_t scr_cap)
{
    __shared__ float ex[4][NF];
    __shared__ float s256f[NF];

    const int tid  = threadIdx.x;
    const int wv   = tid >> 6;
    const int lane = tid & 63;

    s256f[tid]       = s256g[tid];
    s256f[tid + 256] = s256g[tid + 256];
    __syncthreads();

    float strd = p_stride[0];
    float wl   = fminf(fmaxf(p_winlen[0], (float)(512.0 / 20.0)), 512.0f);
    float wpow = p_winpow[0];
    const bool dopow = (wpow != 1.0f);

    double strd64 = fmin(fmax((double)strd, 0.0), 512.0);
    const bool intstride = (floor(strd64) == strd64);

    const int rb = bitrev6(lane);
    const int b  = blockIdx.y;
    const float* xb = x + (size_t)b * LL;

    // hoisted twiddles
    float stc[5], sts[5];
#pragma unroll
    for (int s = 1; s < 6; ++s) {
        int h = 1 << s;
        sincosf(-PI_F * (float)(lane & (h - 1)) / (float)h, &sts[s - 1], &stc[s - 1]);
    }
    float wac[7], was[7];
    {
        float b1s, b1c;
        sincosf(-(TWO_PI / 512.0f) * (float)lane, &b1s, &b1c);
        float cc = b1c, ss = b1s;
        wac[0] = cc; was[0] = ss;
#pragma unroll
        for (int a = 1; a < 7; ++a) {
            float nc = cc * b1c - ss * b1s, ns = cc * b1s + ss * b1c;
            cc = nc; ss = ns; wac[a] = cc; was[a] = ss;
        }
    }
    // hoisted window (frac == 0 for integer stride)
    float ww8[8];
    if (intstride) fast_weights(0.0f, wl, wpow, dopow, rb, ww8);

    const int tbase = blockIdx.x * (4 * FPW) + wv * FPW;
#pragma unroll 1
    for (int ft = 0; ft < FPW; ++ft) {
        int t = tbase + ft;
        bool active = (t < TT);
        double frame64 = strd64 * (double)t;
        int i0 = (int)floor(frame64);
        float frac = (float)(frame64 - floor(frame64));

        float wwf[8];
        if (intstride) {
#pragma unroll
            for (int a = 0; a < 8; ++a) wwf[a] = ww8[a];
        } else {
            fast_weights(frac, wl, wpow, dopow, rb, wwf);
        }

        float2 S[8];
        float nyq;
        compute_frame(xb, i0, frac, wl, wpow, dopow, wwf, s256f, ex[wv],
                      stc, sts, wac, was, lane, rb, active, S, &nyq);

        if (active) {
            size_t basez = ((size_t)b * TT + t) * NF;
#pragma unroll
            for (int j = 0; j < 8; ++j) {
                float2 vv = S[j];
                if (j == 0 && lane == 0) vv.y = neg_zero(); // gold: -(+0) = -0.0
                if (j == 4 && lane == 0) vv.y = nyq;        // gold npyv Nyquist
                size_t f = (size_t)(lane + 64 * j);
                if (basez + f < scr_cap) scr[basez + f] = vv;
            }
        }
    }
}

// ---------------------------------------------------------------------------
__global__ __launch_bounds__(256) void dstft_epilogue(
    const float2* __restrict__ scr, size_t scr_cap,
    float* __restrict__ out, size_t oe, int layoutB)
{
    __shared__ float2 tile[32][33];
    const int tx = threadIdx.x;          // 0..31
    const int ty = threadIdx.y;          // 0..7
    const int t0 = blockIdx.x * 32;
    const int f0 = blockIdx.y * 32;
    const int b  = blockIdx.z;

#pragma unroll
    for (int i = 0; i < 4; ++i) {
        int tl = ty + 8 * i;
        int t  = t0 + tl;
        float2 v = make_float2(0.0f, 0.0f);
        size_t si = ((size_t)b * TT + t) * NF + (f0 + tx);
        if (t < TT && si < scr_cap) v = scr[si];
        tile[tl][tx] = v;
    }
    __syncthreads();

    const size_t off_stft  = SPEC_N;
    const size_t off_real  = layoutB ? (SPEC_N + BNT) : (SPEC_N + 2 * BNT);
    const size_t off_imag  = off_real + BNT;
    const size_t off_phase = off_imag + BNT;

#pragma unroll
    for (int i = 0; i < 4; ++i) {
        int fl = ty + 8 * i;
        int f  = f0 + fl;
        int t  = t0 + tx;
        if (t >= TT) continue;
        float2 v = tile[tx][fl];
        size_t o = ((size_t)b * NF + f) * TT + t;
        if (off_real + o < oe) out[off_real + o] = v.x;
        if (off_imag + o < oe) out[off_imag + o] = v.y;
        if (layoutB) {
            if (off_stft + o < oe) out[off_stft + o] = v.x;
        } else {
            size_t os = off_stft + 2 * o;
            if (os + 1 < oe) *reinterpret_cast<float2*>(out + os) = v;
        }
        if (f < FF) {
            size_t o2 = ((size_t)b * FF + f) * TT + t;
            if (o2 < oe) out[o2] = sqrtf(v.x * v.x + v.y * v.y) + 1.1920929e-7f;
            if (off_phase + o2 < oe) out[off_phase + o2] = atan2f(v.y, v.x);
        }
    }
}

// ---------------------------------------------------------------------------
// Fallback (ws too small): fused compute + direct writes.
__global__ __launch_bounds__(256) void dstft_fused(
    const float* __restrict__ x,
    const float* __restrict__ p_stride,
    const float* __restrict__ p_winlen,
    const float* __restrict__ p_winpow,
    float* __restrict__ out, size_t oe, int layoutB)
{
    __shared__ float ex[4][NF];
    __shared__ float s256f[NF];

    const int tid  = threadIdx.x;
    const int wv   = tid >> 6;
    const int lane = tid & 63;

    for (int k = tid; k < NF; k += 256)
        s256f[k] = (float)sin((double)theta32(256 * k));
    __syncthreads();

    float strd = p_stride[0];
    float wl   = fminf(fmaxf(p_winlen[0], (float)(512.0 / 20.0)), 512.0f);
    float wpow = p_winpow[0];
    const bool dopow = (wpow != 1.0f);

    double strd64 = fmin(fmax((double)strd, 0.0), 512.0);
    const int rb = bitrev6(lane);
    const int b  = blockIdx.y;
    const float* xb = x + (size_t)b * LL;

    float stc[5], sts[5];
#pragma unroll
    for (int s = 1; s < 6; ++s) {
        int h = 1 << s;
        sincosf(-PI_F * (float)(lane & (h - 1)) / (float)h, &sts[s - 1], &stc[s - 1]);
    }
    float wac[7], was[7];
    {
        float b1s, b1c;
        sincosf(-(TWO_PI / 512.0f) * (float)lane, &b1s, &b1c);
        float cc = b1c, ss = b1s;
        wac[0] = cc; was[0] = ss;
#pragma unroll
        for (int a = 1; a < 7; ++a) {
            float nc = cc * b1c - ss * b1s, ns = cc * b1s + ss * b1c;
            cc = nc; ss = ns; wac[a] = cc; was[a] = ss;
        }
    }

    const int t = blockIdx.x * 4 + wv;
    const bool active = (t < TT);
    double frame64 = strd64 * (double)t;
    int i0 = (int)floor(frame64);
    float frac = (float)(frame64 - floor(frame64));

    float wwf[8];
    fast_weights(frac, wl, wpow, dopow, rb, wwf);

    float2 S[8];
    float nyq;
    compute_frame(xb, i0, frac, wl, wpow, dopow, wwf, s256f, ex[wv],
                  stc, sts, wac, was, lane, rb, active, S, &nyq);

    if (active) {
        const size_t off_stft  = SPEC_N;
        const size_t off_real  = layoutB ? (SPEC_N + BNT) : (SPEC_N + 2 * BNT);
        const size_t off_imag  = off_real + BNT;
        const size_t off_phase = off_imag + BNT;
#pragma unroll
        for (int j = 0; j < 8; ++j) {
            float2 vv = S[j];
            if (j == 0 && lane == 0) vv.y = neg_zero();
            if (j == 4 && lane == 0) vv.y = nyq;
            int f = lane + 64 * j;
            size_t o = ((size_t)b * NF + f) * TT + t;
            if (off_real + o < oe) out[off_real + o] = vv.x;
            if (off_imag + o < oe) out[off_imag + o] = vv.y;
            if (layoutB) {
                if (off_stft + o < oe) out[off_stft + o] = vv.x;
            } else {
                size_t os = off_stft + 2 * o;
                if (os + 1 < oe) { out[os] = vv.x; out[os + 1] = vv.y; }
            }
            if (f < FF) {
                size_t o2 = ((size_t)b * FF + f) * TT + t;
                if (o2 < oe) out[o2] = sqrtf(vv.x * vv.x + vv.y * vv.y) + 1.1920929e-7f;
                if (off_phase + o2 < oe) out[off_phase + o2] = atan2f(vv.y, vv.x);
            }
        }
    }
}

// ---------------------------------------------------------------------------
extern "C" void kernel_launch(void* const* d_in, const int* in_sizes, int n_in,
                              void* d_out, int out_size, void* d_ws, size_t ws_size,
                              hipStream_t stream)
{
    const float* x  = (const float*)d_in[0];
    const float* ps = (const float*)d_in[1];
    const float* pw = (const float*)d_in[2];
    const float* pp = (const float*)d_in[3];
    float* out = (float*)d_out;

    const size_t totalA = 2 * SPEC_N + 4 * BNT;   // 40,961,256
    int layoutB = ((size_t)out_size == totalA) ? 0 : 1;   // confirmed: B

    const size_t oe = (size_t)out_size;
    const size_t scrBytes = BNT * sizeof(float2);          // 65.5 MB
    const size_t needWs   = scrBytes + NF * sizeof(float); // + sin table
    const bool use_ws = (d_ws != nullptr) && (ws_size >= needWs);

    if (use_ws) {
        float2* scr   = (float2*)d_ws;
        float*  s256g = (float*)((char*)d_ws + scrBytes);
        dstft_sin256<<<1, NF, 0, stream>>>(s256g);
        const int fpb = 4 * FPW;   // frames per block
        dstft_fft_kernel<<<dim3((TT + fpb - 1) / fpb, BB), 256, 0, stream>>>(
            x, ps, pw, pp, s256g, scr, BNT);
        dstft_epilogue<<<dim3((TT + 31) / 32, NF / 32, BB), dim3(32, 8), 0, stream>>>(
            scr, BNT, out, oe, layoutB);
    } else {
        dstft_fused<<<dim3((TT + 3) / 4, BB), 256, 0, stream>>>(
            x, ps, pw, pp, out, oe, layoutB);
    }
}

// Round 18
// 158.127 us; speedup vs baseline: 1.3150x; 1.3150x over previous
//
#include <hip/hip_runtime.h>
#include <math.h>

#define BB 4
#define LL 512000
#define NF 512
#define TT 3997
#define FF 257
#define TWO_PI 6.28318530717958647692f
#define PI_F 3.14159265358979323846f
// fl32(2*pi) — what the f32 numpy port uses building theta and window args:
#define TPI_F32 6.28318548202514648f

static const size_t SPEC_N = (size_t)BB * FF * TT;   // 4,108,916
static const size_t BNT    = (size_t)BB * NF * TT;   // 8,185,856
// layout B (confirmed r11): spec | stft real-part (BNT) | real | imag | phase

#define AB_IM  3.0e-5f
#define RE_MAX 1.0e-4f
#define Z2_MIN 1.0e-8f

__device__ __forceinline__ float neg_zero() { return __uint_as_float(0x80000000u); }

// Barriered ops: exactly one IEEE-RN rounding each (stops -ffp-contract=fast
// from fusing where numpy has separate ops).
__device__ __forceinline__ float mulrn(float a, float b) { float t = a * b; asm("" : "+v"(t)); return t; }
__device__ __forceinline__ float addrn(float a, float b) { float t = a + b; asm("" : "+v"(t)); return t; }
// Single-rounded fused a*b+c (npyv_muladd on AVX512 = FMA):
__device__ __forceinline__ float fmarn(float a, float b, float c) { float t = fmaf(a, b, c); asm("" : "+v"(t)); return t; }

// np f32 theta: fl32(fl32(2pi)*k)/512  (k = f*n < 2^24 exact; /512 exact)
__device__ __forceinline__ float theta32(int k) {
    return mulrn(TPI_F32, (float)k) / 512.0f;
}

__device__ __forceinline__ int bitrev6(int l) { return (int)(__brev((unsigned)l) >> 26); }

// exrow swizzle: XOR bits5-7 onto bits0-2 — makes the 8b+a staging writes
// 2-way (free) and npyv-dot reads conflict-free. Bijective.
__device__ __forceinline__ int exr_idx(int n) { return n ^ ((n >> 5) & 7); }

// Intra-wave LDS wait for the per-wave-divergent gold branch ONLY (R13-proven
// pattern; __syncthreads would deadlock there). Rule #18: sched_barrier after.
#define GOLD_SYNC() do { asm volatile("s_waitcnt lgkmcnt(0)" ::: "memory"); \
                         __builtin_amdgcn_sched_barrier(0); } while (0)

// _mm512_reduce_add_ps tree over 16 partials held by lanes base..base+15
__device__ __forceinline__ float hsum16(float s, int base) {
    float q[4];
#pragma unroll
    for (int k = 0; k < 4; ++k) {
        float a = addrn(__shfl(s, base + k),     __shfl(s, base + k + 8));
        float b = addrn(__shfl(s, base + k + 4), __shfl(s, base + k + 12));
        q[k] = addrn(a, b);
    }
    return addrn(addrn(q[0], q[2]), addrn(q[1], q[3]));
}

// ---------------------------------------------------------------------------
__global__ void dstft_sin256(float* __restrict__ s256g)
{
    int n = threadIdx.x;   // 512 threads
    s256g[n] = (float)sin((double)theta32(256 * n));
}

// ---------------------------------------------------------------------------
// One frame: loads + register FFT (8x64, f = lane + 64*j) + nyq + gold patches.
// S[8] out; nyq out. exrow is wave-private LDS (NF floats, swizzled).
// Fast-path LDS ordering uses __syncthreads (uniform, compiler-safe); the
// per-wave-divergent gold branch uses GOLD_SYNC (R13-proven).
__device__ __forceinline__ void dstft_frame_compute(
    const float* __restrict__ xb, int i0, float frac,
    float wl, float wpow, bool dopow,
    const float* __restrict__ s256f, float* __restrict__ exrow,
    int lane, int rb, bool active, float2* S, float* nyq_out)
{
    // ---- fast window weights for this lane's slots n = 8*rb + a
    float wwf[8];
    {
        float shift = (wl - 511.0f) * 0.5f;
        float lower = floorf((511.0f - wl) * 0.5f);
        float upper = ceilf ((511.0f + wl) * 0.5f);
        float psum = 0.0f;
#pragma unroll
        for (int a = 0; a < 8; ++a) {
            int n = 8 * rb + a;
            float base = (float)n - frac;
            float w = 0.0f;
            if (base > lower && base < upper)
                w = 0.5f - 0.5f * cosf(TWO_PI * (base + shift) / wl);
            wwf[a] = w;
            psum += w;
        }
#pragma unroll
        for (int off = 32; off > 0; off >>= 1) psum += __shfl_xor(psum, off);
        float inv = 1.0f / psum;
#pragma unroll
        for (int a = 0; a < 8; ++a) {
            float w = wwf[a] * inv;
            if (dopow) w = powf(w, wpow);
            wwf[a] = w;
        }
    }

    // ---- loads: 8 contiguous floats at i0 + 8*rb; taps into z + exrow
    int nb = i0 + 8 * rb;
    float2 z[4];
#pragma unroll
    for (int a = 0; a < 8; ++a) {
        int idx = nb + a;
        float xv = (active && idx >= 0 && idx < LL) ? xb[idx] : 0.0f;
        float tapv = xv * wwf[a];
        exrow[exr_idx(8 * rb + a)] = tapv;
        if ((a & 1) == 0) z[a >> 1].x = tapv;
        else              z[a >> 1].y = tapv;
    }

    // ---- 4 packed real-pair 64-pt DIT DFTs across lanes
    // stage h=1 (w=1)
#pragma unroll
    for (int c = 0; c < 4; ++c) {
        float px = __shfl_xor(z[c].x, 1), py = __shfl_xor(z[c].y, 1);
        if (lane & 1) { z[c].x = px - z[c].x; z[c].y = py - z[c].y; }
        else          { z[c].x += px;         z[c].y += py; }
    }
    // stages h=2..32 (twiddle recomputed inline)
#pragma unroll
    for (int s = 1; s < 6; ++s) {
        int h = 1 << s;
        float ws, wc;
        sincosf(-PI_F * (float)(lane & (h - 1)) / (float)h, &ws, &wc);
#pragma unroll
        for (int c = 0; c < 4; ++c) {
            float px = __shfl_xor(z[c].x, h), py = __shfl_xor(z[c].y, h);
            if (lane & h) {
                float wx = wc * z[c].x - ws * z[c].y;
                float wy = wc * z[c].y + ws * z[c].x;
                z[c].x = px - wx; z[c].y = py - wy;
            } else {
                float wx = wc * px - ws * py;
                float wy = wc * py + ws * px;
                z[c].x += wx; z[c].y += wy;
            }
        }
    }
    // ---- hermitian unpack + twiddle W512^{a*lane} (2-reg chain)
    float2 Bv[8];
    {
        int srcl = (64 - lane) & 63;
#pragma unroll
        for (int c = 0; c < 4; ++c) {
            float rx = __shfl(z[c].x, srcl), ry = __shfl(z[c].y, srcl);
            Bv[2 * c]     = make_float2(0.5f * (z[c].x + rx), 0.5f * (z[c].y - ry));
            Bv[2 * c + 1] = make_float2(0.5f * (z[c].y + ry), -0.5f * (z[c].x - rx));
        }
        float b1s, b1c;
        sincosf(-(TWO_PI / 512.0f) * (float)lane, &b1s, &b1c);
        float cc = b1c, ss = b1s;
#pragma unroll
        for (int a = 1; a < 8; ++a) {
            float vx = Bv[a].x, vy = Bv[a].y;
            Bv[a] = make_float2(vx * cc - vy * ss, vx * ss + vy * cc);
            if (a < 7) {
                float nc = cc * b1c - ss * b1s;
                float ns = cc * b1s + ss * b1c;
                cc = nc; ss = ns;
            }
        }
    }
    // ---- 8-pt complex DFT over slots: S[j] for f = lane + 64*j
    {
        const float Cq = 0.70710678118654752440f;
        float ex0 = Bv[0].x + Bv[4].x, ey0 = Bv[0].y + Bv[4].y;
        float dx0 = Bv[0].x - Bv[4].x, dy0 = Bv[0].y - Bv[4].y;
        float ex1 = Bv[2].x + Bv[6].x, ey1 = Bv[2].y + Bv[6].y;
        float dx1 = Bv[2].x - Bv[6].x, dy1 = Bv[2].y - Bv[6].y;
        float2 E0 = make_float2(ex0 + ex1, ey0 + ey1);
        float2 E2 = make_float2(ex0 - ex1, ey0 - ey1);
        float2 E1 = make_float2(dx0 + dy1, dy0 - dx1);
        float2 E3 = make_float2(dx0 - dy1, dy0 + dx1);
        float ox0 = Bv[1].x + Bv[5].x, oy0 = Bv[1].y + Bv[5].y;
        float qx0 = Bv[1].x - Bv[5].x, qy0 = Bv[1].y - Bv[5].y;
        float ox1 = Bv[3].x + Bv[7].x, oy1 = Bv[3].y + Bv[7].y;
        float qx1 = Bv[3].x - Bv[7].x, qy1 = Bv[3].y - Bv[7].y;
        float2 O0 = make_float2(ox0 + ox1, oy0 + oy1);
        float2 O2 = make_float2(ox0 - ox1, oy0 - oy1);
        float2 O1 = make_float2(qx0 + qy1, qy0 - qx1);
        float2 O3 = make_float2(qx0 - qy1, qy0 + qx1);
        float2 T0 = O0;
        float2 T1 = make_float2(Cq * (O1.x + O1.y), Cq * (O1.y - O1.x));
        float2 T2 = make_float2(O2.y, -O2.x);
        float2 T3 = make_float2(Cq * (O3.y - O3.x), -Cq * (O3.x + O3.y));
        S[0] = make_float2(E0.x + T0.x, E0.y + T0.y);
        S[4] = make_float2(E0.x - T0.x, E0.y - T0.y);
        S[1] = make_float2(E1.x + T1.x, E1.y + T1.y);
        S[5] = make_float2(E1.x - T1.x, E1.y - T1.y);
        S[2] = make_float2(E2.x + T2.x, E2.y + T2.y);
        S[6] = make_float2(E2.x - T2.x, E2.y - T2.y);
        S[3] = make_float2(E3.x + T3.x, E3.y + T3.y);
        S[7] = make_float2(E3.x - T3.x, E3.y - T3.y);
    }
    __syncthreads();   // tap staging visible (uniform path — compiler-safe)

    // ---- imag[256] = -(npyv forward dot of taps with s256f) — always
    {
        float s = 0.0f;
        if (lane < 16) {
#pragma unroll 1
            for (int i = 0; i < 8; ++i) {
                int base = 64 * i + lane;
                s = fmarn(exrow[exr_idx(base +  0)], s256f[base +  0], s);
                s = fmarn(exrow[exr_idx(base + 16)], s256f[base + 16], s);
                s = fmarn(exrow[exr_idx(base + 32)], s256f[base + 32], s);
                s = fmarn(exrow[exr_idx(base + 48)], s256f[base + 48], s);
            }
        }
        *nyq_out = -hsum16(s, 0);
    }

    // ---- flag scan: f = lane + 64*j (phase bins f<=256 only)
    unsigned long long flags[5];
    unsigned long long anyf = 0ULL;
#pragma unroll
    for (int j = 0; j < 5; ++j) {
        float2 vv = S[j];
        bool flg = false;
        if (active) {
            if (j == 0 && lane == 0)      flg = fabsf(vv.x) < RE_MAX;   // f=0
            else if (j == 4)              flg = (lane == 0) && (fabsf(vv.x) < RE_MAX); // f=256
            else                          flg = (fabsf(vv.y) < AB_IM && vv.x < RE_MAX) ||
                                                (vv.x * vv.x + vv.y * vv.y < Z2_MIN);
        }
        flags[j] = __ballot(flg);
        anyf |= flags[j];
    }

    if (anyf) {   // per-wave divergent: GOLD_SYNC only (no __syncthreads here)
        // ---- gold window (f32 ops, f64-rounded cos) — R13-verified sequence
        float g_shift = mulrn(addrn(wl - 512.0f, 1.0f), 0.5f);
        float g_lower = floorf(mulrn(511.0f - wl, 0.5f));
        float g_upper = ceilf (mulrn(511.0f + wl, 0.5f));
        float gw[8];
#pragma unroll
        for (int a = 0; a < 8; ++a) {
            int n = 8 * rb + a;
            float base = (float)n - frac;
            float w = 0.0f;
            if (base > g_lower && base < g_upper) {
                float arg = mulrn(TPI_F32, addrn(base, g_shift)) / wl;
                w = 0.5f - mulrn(0.5f, (float)cos((double)arg));
            }
            gw[a] = w;
            exrow[exr_idx(n)] = w;
        }
        GOLD_SYNC();
        // psum: np.sum(axis=0) = strictly sequential over n
        float ps = 0.0f;
        if (lane == 0) {
#pragma unroll 1
            for (int n = 0; n < NF; ++n) ps = addrn(ps, exrow[exr_idx(n)]);
        }
        ps = __shfl(ps, 0);
#pragma unroll
        for (int a = 0; a < 8; ++a) {
            int n = 8 * rb + a;
            int idx = nb + a;
            float xv = (active && idx >= 0 && idx < LL) ? xb[idx] : 0.0f;
            float w = gw[a] / ps;                  // np: tap / sum (f32 div)
            if (dopow) w = powf(w, wpow);
            exrow[exr_idx(n)] = mulrn(xv, w);      // gold tapered
        }
        GOLD_SYNC();

#pragma unroll
        for (int j = 0; j < 5; ++j) {
            unsigned long long m = flags[j];
            while (m) {
                int src = (int)(__ffsll(m) - 1);
                m &= m - 1;
                int ff = src + 64 * j;
                // lanes 0-15: sin partials; 16-31: cos; FORWARD npyv chain
                float s = 0.0f;
                if (lane < 32) {
                    int L = lane & 15;
                    bool isCos = lane >= 16;
#pragma unroll 1
                    for (int i = 0; i < 8; ++i) {
                        int base = 64 * i + L;
#pragma unroll
                        for (int Bq = 0; Bq < 4; ++Bq) {
                            int n = base + 16 * Bq;
                            double sv, cv;
                            sincos((double)theta32(ff * n), &sv, &cv);
                            s = fmarn(exrow[exr_idx(n)], isCos ? (float)cv : (float)sv, s);
                        }
                    }
                }
                float im = hsum16(s, 0);
                float re = hsum16(s, 16);
                if (lane == src) S[j] = make_float2(re, -im);
            }
        }
        // gold nyq from gold taps
        {
            float s = 0.0f;
            if (lane < 16) {
#pragma unroll 1
                for (int i = 0; i < 8; ++i) {
                    int base = 64 * i + lane;
                    s = fmarn(exrow[exr_idx(base +  0)], s256f[base +  0], s);
                    s = fmarn(exrow[exr_idx(base + 16)], s256f[base + 16], s);
                    s = fmarn(exrow[exr_idx(base + 32)], s256f[base + 32], s);
                    s = fmarn(exrow[exr_idx(base + 48)], s256f[base + 48], s);
                }
            }
            *nyq_out = -hsum16(s, 0);
        }
        GOLD_SYNC();
    }
}

// ---------------------------------------------------------------------------
__global__ __launch_bounds__(256) void dstft_fft_kernel(
    const float* __restrict__ x,
    const float* __restrict__ p_stride,
    const float* __restrict__ p_winlen,
    const float* __restrict__ p_winpow,
    const float* __restrict__ s256g,
    float2* __restrict__ scr, size_t scr_cap)
{
    __shared__ float ex[4][NF];
    __shared__ float s256f[NF];

    const int tid  = threadIdx.x;
    const int wv   = tid >> 6;
    const int lane = tid & 63;

    s256f[tid]       = s256g[tid];
    s256f[tid + 256] = s256g[tid + 256];
    __syncthreads();

    float strd = p_stride[0];
    float wl   = fminf(fmaxf(p_winlen[0], (float)(512.0 / 20.0)), 512.0f);
    float wpow = p_winpow[0];
    const bool dopow = (wpow != 1.0f);

    double strd64 = fmin(fmax((double)strd, 0.0), 512.0);

    const int rb = bitrev6(lane);
    const int b  = blockIdx.y;
    const float* xb = x + (size_t)b * LL;

    const int t = blockIdx.x * 4 + wv;
    const bool active = (t < TT);
    double frame64 = strd64 * (double)t;
    int i0 = (int)floor(frame64);
    float frac = (float)(frame64 - floor(frame64));

    float2 S[8];
    float nyq;
    dstft_frame_compute(xb, i0, frac, wl, wpow, dopow, s256f, ex[wv],
                        lane, rb, active, S, &nyq);

    if (active) {
        size_t basez = ((size_t)b * TT + t) * NF;
#pragma unroll
        for (int j = 0; j < 8; ++j) {
            float2 vv = S[j];
            if (j == 0 && lane == 0) vv.y = neg_zero(); // gold: -(+0) = -0.0
            if (j == 4 && lane == 0) vv.y = nyq;        // gold npyv Nyquist
            size_t f = (size_t)(lane + 64 * j);
            if (basez + f < scr_cap) scr[basez + f] = vv;
        }
    }
}

// ---------------------------------------------------------------------------
__global__ __launch_bounds__(256) void dstft_epilogue(
    const float2* __restrict__ scr, size_t scr_cap,
    float* __restrict__ out, size_t oe, int layoutB)
{
    __shared__ float2 tile[32][33];
    const int tx = threadIdx.x;          // 0..31
    const int ty = threadIdx.y;          // 0..7
    const int t0 = blockIdx.x * 32;
    const int f0 = blockIdx.y * 32;
    const int b  = blockIdx.z;

#pragma unroll
    for (int i = 0; i < 4; ++i) {
        int tl = ty + 8 * i;
        int t  = t0 + tl;
        float2 v = make_float2(0.0f, 0.0f);
        size_t si = ((size_t)b * TT + t) * NF + (f0 + tx);
        if (t < TT && si < scr_cap) v = scr[si];
        tile[tl][tx] = v;
    }
    __syncthreads();

    const size_t off_stft  = SPEC_N;
    const size_t off_real  = layoutB ? (SPEC_N + BNT) : (SPEC_N + 2 * BNT);
    const size_t off_imag  = off_real + BNT;
    const size_t off_phase = off_imag + BNT;

#pragma unroll
    for (int i = 0; i < 4; ++i) {
        int fl = ty + 8 * i;
        int f  = f0 + fl;
        int t  = t0 + tx;
        if (t >= TT) continue;
        float2 v = tile[tx][fl];
        size_t o = ((size_t)b * NF + f) * TT + t;
        if (off_real + o < oe) out[off_real + o] = v.x;
        if (off_imag + o < oe) out[off_imag + o] = v.y;
        if (layoutB) {
            if (off_stft + o < oe) out[off_stft + o] = v.x;
        } else {
            size_t os = off_stft + 2 * o;
            if (os + 1 < oe) *reinterpret_cast<float2*>(out + os) = v;
        }
        if (f < FF) {
            size_t o2 = ((size_t)b * FF + f) * TT + t;
            if (o2 < oe) out[o2] = sqrtf(v.x * v.x + v.y * v.y) + 1.1920929e-7f;
            if (off_phase + o2 < oe) out[off_phase + o2] = atan2f(v.y, v.x);
        }
    }
}

// ---------------------------------------------------------------------------
// Fallback (ws too small): fused compute + direct writes.
__global__ __launch_bounds__(256) void dstft_fused(
    const float* __restrict__ x,
    const float* __restrict__ p_stride,
    const float* __restrict__ p_winlen,
    const float* __restrict__ p_winpow,
    float* __restrict__ out, size_t oe, int layoutB)
{
    __shared__ float ex[4][NF];
    __shared__ float s256f[NF];

    const int tid  = threadIdx.x;
    const int wv   = tid >> 6;
    const int lane = tid & 63;

    for (int k = tid; k < NF; k += 256)
        s256f[k] = (float)sin((double)theta32(256 * k));
    __syncthreads();

    float strd = p_stride[0];
    float wl   = fminf(fmaxf(p_winlen[0], (float)(512.0 / 20.0)), 512.0f);
    float wpow = p_winpow[0];
    const bool dopow = (wpow != 1.0f);

    double strd64 = fmin(fmax((double)strd, 0.0), 512.0);
    const int rb = bitrev6(lane);
    const int b  = blockIdx.y;
    const float* xb = x + (size_t)b * LL;

    const int t = blockIdx.x * 4 + wv;
    const bool active = (t < TT);
    double frame64 = strd64 * (double)t;
    int i0 = (int)floor(frame64);
    float frac = (float)(frame64 - floor(frame64));

    float2 S[8];
    float nyq;
    dstft_frame_compute(xb, i0, frac, wl, wpow, dopow, s256f, ex[wv],
                        lane, rb, active, S, &nyq);

    if (active) {
        const size_t off_stft  = SPEC_N;
        const size_t off_real  = layoutB ? (SPEC_N + BNT) : (SPEC_N + 2 * BNT);
        const size_t off_imag  = off_real + BNT;
        const size_t off_phase = off_imag + BNT;
#pragma unroll
        for (int j = 0; j < 8; ++j) {
            float2 vv = S[j];
            if (j == 0 && lane == 0) vv.y = neg_zero();
            if (j == 4 && lane == 0) vv.y = nyq;
            int f = lane + 64 * j;
            size_t o = ((size_t)b * NF + f) * TT + t;
            if (off_real + o < oe) out[off_real + o] = vv.x;
            if (off_imag + o < oe) out[off_imag + o] = vv.y;
            if (layoutB) {
                if (off_stft + o < oe) out[off_stft + o] = vv.x;
            } else {
                size_t os = off_stft + 2 * o;
                if (os + 1 < oe) { out[os] = vv.x; out[os + 1] = vv.y; }
            }
            if (f < FF) {
                size_t o2 = ((size_t)b * FF + f) * TT + t;
                if (o2 < oe) out[o2] = sqrtf(vv.x * vv.x + vv.y * vv.y) + 1.1920929e-7f;
                if (off_phase + o2 < oe) out[off_phase + o2] = atan2f(vv.y, vv.x);
            }
        }
    }
}

// ---------------------------------------------------------------------------
extern "C" void kernel_launch(void* const* d_in, const int* in_sizes, int n_in,
                              void* d_out, int out_size, void* d_ws, size_t ws_size,
                              hipStream_t stream)
{
    const float* x  = (const float*)d_in[0];
    const float* ps = (const float*)d_in[1];
    const float* pw = (const float*)d_in[2];
    const float* pp = (const float*)d_in[3];
    float* out = (float*)d_out;

    const size_t totalA = 2 * SPEC_N + 4 * BNT;   // 40,961,256
    int layoutB = ((size_t)out_size == totalA) ? 0 : 1;   // confirmed: B

    const size_t oe = (size_t)out_size;
    const size_t scrBytes = BNT * sizeof(float2);          // 65.5 MB
    const size_t needWs   = scrBytes + NF * sizeof(float); // + sin table
    const bool use_ws = (d_ws != nullptr) && (ws_size >= needWs);

    if (use_ws) {
        float2* scr   = (float2*)d_ws;
        float*  s256g = (float*)((char*)d_ws + scrBytes);
        dstft_sin256<<<1, NF, 0, stream>>>(s256g);
        dstft_fft_kernel<<<dim3((TT + 3) / 4, BB), 256, 0, stream>>>(
            x, ps, pw, pp, s256g, scr, BNT);
        dstft_epilogue<<<dim3((TT + 31) / 32, NF / 32, BB), dim3(32, 8), 0, stream>>>(
            scr, BNT, out, oe, layoutB);
    } else {
        dstft_fused<<<dim3((TT + 3) / 4, BB), 256, 0, stream>>>(
            x, ps, pw, pp, out, oe, layoutB);
    }
}

// Round 19
// 140.170 us; speedup vs baseline: 1.4834x; 1.1281x over previous
//
#include <hip/hip_runtime.h>
#include <math.h>

#define BB 4
#define LL 512000
#define NF 512
#define TT 3997
#define FF 257
#define TWO_PI 6.28318530717958647692f
#define PI_F 3.14159265358979323846f
// fl32(2*pi) — what the f32 numpy port uses building theta and window args:
#define TPI_F32 6.28318548202514648f

static const size_t SPEC_N = (size_t)BB * FF * TT;   // 4,108,916
static const size_t BNT    = (size_t)BB * NF * TT;   // 8,185,856
// layout B (confirmed r11): spec | stft real-part (BNT) | real | imag | phase

#define AB_IM  3.0e-5f
#define RE_MAX 1.0e-4f
#define Z2_MIN 1.0e-8f

__device__ __forceinline__ float neg_zero() { return __uint_as_float(0x80000000u); }

// Barriered ops: exactly one IEEE-RN rounding each (stops -ffp-contract=fast
// from fusing where numpy has separate ops).
__device__ __forceinline__ float mulrn(float a, float b) { float t = a * b; asm("" : "+v"(t)); return t; }
__device__ __forceinline__ float addrn(float a, float b) { float t = a + b; asm("" : "+v"(t)); return t; }
// Single-rounded fused a*b+c (npyv_muladd on AVX512 = FMA):
__device__ __forceinline__ float fmarn(float a, float b, float c) { float t = fmaf(a, b, c); asm("" : "+v"(t)); return t; }

// np f32 theta: fl32(fl32(2pi)*k)/512  (k = f*n < 2^24 exact; /512 exact)
__device__ __forceinline__ float theta32(int k) {
    return mulrn(TPI_F32, (float)k) / 512.0f;
}

__device__ __forceinline__ int bitrev6(int l) { return (int)(__brev((unsigned)l) >> 26); }

// exrow swizzle: XOR bits5-7 onto bits0-2 — makes the 8b+a staging writes
// 2-way (free) and npyv-dot reads conflict-free. Bijective.
__device__ __forceinline__ int exr_idx(int n) { return n ^ ((n >> 5) & 7); }

// Intra-wave LDS wait for the per-wave-divergent gold branch ONLY (R13-proven
// pattern; __syncthreads would deadlock there). Rule #18: sched_barrier after.
#define GOLD_SYNC() do { asm volatile("s_waitcnt lgkmcnt(0)" ::: "memory"); \
                         __builtin_amdgcn_sched_barrier(0); } while (0)

// _mm512_reduce_add_ps tree over 16 partials held by lanes base..base+15
__device__ __forceinline__ float hsum16(float s, int base) {
    float q[4];
#pragma unroll
    for (int k = 0; k < 4; ++k) {
        float a = addrn(__shfl(s, base + k),     __shfl(s, base + k + 8));
        float b = addrn(__shfl(s, base + k + 4), __shfl(s, base + k + 12));
        q[k] = addrn(a, b);
    }
    return addrn(addrn(q[0], q[2]), addrn(q[1], q[3]));
}

// ---------------------------------------------------------------------------
__global__ void dstft_sin256(float* __restrict__ s256g)
{
    int n = threadIdx.x;   // 512 threads
    s256g[n] = (float)sin((double)theta32(256 * n));
}

// ---------------------------------------------------------------------------
// One frame: loads + register FFT (8x64, f = lane + 64*j) + gated nyq + gold
// patches. S[8] out; nyq out (valid only when *nyq_used). exrow = wave-private
// LDS (NF floats, swizzled). Fast path uses __cosf/__sincosf (HW trig, args in
// [-pi,pi]); gold path keeps f64-rounded trig. Sync structure = R18 (proven).
__device__ __forceinline__ void dstft_frame_compute(
    const float* __restrict__ xb, int i0, float frac,
    float wl, float wpow, bool dopow,
    const float* __restrict__ s256f, float* __restrict__ exrow,
    int lane, int rb, bool active, float2* S, float* nyq_out, bool* nyq_used)
{
    // ---- loads first: 8 contiguous floats at i0 + 8*rb (latency hides under
    // the window math below)
    int nb = i0 + 8 * rb;
    float xr[8];
#pragma unroll
    for (int a = 0; a < 8; ++a) {
        int idx = nb + a;
        xr[a] = (active && idx >= 0 && idx < LL) ? xb[idx] : 0.0f;
    }

    // ---- fast window weights for this lane's slots n = 8*rb + a (HW trig)
    float wwf[8];
    {
        float shift = (wl - 511.0f) * 0.5f;
        float lower = floorf((511.0f - wl) * 0.5f);
        float upper = ceilf ((511.0f + wl) * 0.5f);
        float psum = 0.0f;
#pragma unroll
        for (int a = 0; a < 8; ++a) {
            int n = 8 * rb + a;
            float base = (float)n - frac;
            float w = 0.0f;
            if (base > lower && base < upper)
                w = 0.5f - 0.5f * __cosf(TWO_PI * (base + shift) / wl);
            wwf[a] = w;
            psum += w;
        }
#pragma unroll
        for (int off = 32; off > 0; off >>= 1) psum += __shfl_xor(psum, off);
        float inv = 1.0f / psum;
#pragma unroll
        for (int a = 0; a < 8; ++a) {
            float w = wwf[a] * inv;
            if (dopow) w = powf(w, wpow);
            wwf[a] = w;
        }
    }

    // ---- taps into z + exrow
    float2 z[4];
#pragma unroll
    for (int a = 0; a < 8; ++a) {
        float tapv = xr[a] * wwf[a];
        exrow[exr_idx(8 * rb + a)] = tapv;
        if ((a & 1) == 0) z[a >> 1].x = tapv;
        else              z[a >> 1].y = tapv;
    }

    // ---- 4 packed real-pair 64-pt DIT DFTs across lanes
    // stage h=1 (w=1)
#pragma unroll
    for (int c = 0; c < 4; ++c) {
        float px = __shfl_xor(z[c].x, 1), py = __shfl_xor(z[c].y, 1);
        if (lane & 1) { z[c].x = px - z[c].x; z[c].y = py - z[c].y; }
        else          { z[c].x += px;         z[c].y += py; }
    }
    // stages h=2..32 (HW trig twiddle, |arg| <= pi)
#pragma unroll
    for (int s = 1; s < 6; ++s) {
        int h = 1 << s;
        float ws, wc;
        __sincosf(-PI_F * (float)(lane & (h - 1)) / (float)h, &ws, &wc);
#pragma unroll
        for (int c = 0; c < 4; ++c) {
            float px = __shfl_xor(z[c].x, h), py = __shfl_xor(z[c].y, h);
            if (lane & h) {
                float wx = wc * z[c].x - ws * z[c].y;
                float wy = wc * z[c].y + ws * z[c].x;
                z[c].x = px - wx; z[c].y = py - wy;
            } else {
                float wx = wc * px - ws * py;
                float wy = wc * py + ws * px;
                z[c].x += wx; z[c].y += wy;
            }
        }
    }
    // ---- hermitian unpack + twiddle W512^{a*lane} (2-reg chain)
    float2 Bv[8];
    {
        int srcl = (64 - lane) & 63;
#pragma unroll
        for (int c = 0; c < 4; ++c) {
            float rx = __shfl(z[c].x, srcl), ry = __shfl(z[c].y, srcl);
            Bv[2 * c]     = make_float2(0.5f * (z[c].x + rx), 0.5f * (z[c].y - ry));
            Bv[2 * c + 1] = make_float2(0.5f * (z[c].y + ry), -0.5f * (z[c].x - rx));
        }
        float b1s, b1c;
        __sincosf(-(TWO_PI / 512.0f) * (float)lane, &b1s, &b1c);
        float cc = b1c, ss = b1s;
#pragma unroll
        for (int a = 1; a < 8; ++a) {
            float vx = Bv[a].x, vy = Bv[a].y;
            Bv[a] = make_float2(vx * cc - vy * ss, vx * ss + vy * cc);
            if (a < 7) {
                float nc = cc * b1c - ss * b1s;
                float ns = cc * b1s + ss * b1c;
                cc = nc; ss = ns;
            }
        }
    }
    // ---- 8-pt complex DFT over slots: S[j] for f = lane + 64*j
    {
        const float Cq = 0.70710678118654752440f;
        float ex0 = Bv[0].x + Bv[4].x, ey0 = Bv[0].y + Bv[4].y;
        float dx0 = Bv[0].x - Bv[4].x, dy0 = Bv[0].y - Bv[4].y;
        float ex1 = Bv[2].x + Bv[6].x, ey1 = Bv[2].y + Bv[6].y;
        float dx1 = Bv[2].x - Bv[6].x, dy1 = Bv[2].y - Bv[6].y;
        float2 E0 = make_float2(ex0 + ex1, ey0 + ey1);
        float2 E2 = make_float2(ex0 - ex1, ey0 - ey1);
        float2 E1 = make_float2(dx0 + dy1, dy0 - dx1);
        float2 E3 = make_float2(dx0 - dy1, dy0 + dx1);
        float ox0 = Bv[1].x + Bv[5].x, oy0 = Bv[1].y + Bv[5].y;
        float qx0 = Bv[1].x - Bv[5].x, qy0 = Bv[1].y - Bv[5].y;
        float ox1 = Bv[3].x + Bv[7].x, oy1 = Bv[3].y + Bv[7].y;
        float qx1 = Bv[3].x - Bv[7].x, qy1 = Bv[3].y - Bv[7].y;
        float2 O0 = make_float2(ox0 + ox1, oy0 + oy1);
        float2 O2 = make_float2(ox0 - ox1, oy0 - oy1);
        float2 O1 = make_float2(qx0 + qy1, qy0 - qx1);
        float2 O3 = make_float2(qx0 - qy1, qy0 + qx1);
        float2 T0 = O0;
        float2 T1 = make_float2(Cq * (O1.x + O1.y), Cq * (O1.y - O1.x));
        float2 T2 = make_float2(O2.y, -O2.x);
        float2 T3 = make_float2(Cq * (O3.y - O3.x), -Cq * (O3.x + O3.y));
        S[0] = make_float2(E0.x + T0.x, E0.y + T0.y);
        S[4] = make_float2(E0.x - T0.x, E0.y - T0.y);
        S[1] = make_float2(E1.x + T1.x, E1.y + T1.y);
        S[5] = make_float2(E1.x - T1.x, E1.y - T1.y);
        S[2] = make_float2(E2.x + T2.x, E2.y + T2.y);
        S[6] = make_float2(E2.x - T2.x, E2.y - T2.y);
        S[3] = make_float2(E3.x + T3.x, E3.y + T3.y);
        S[7] = make_float2(E3.x - T3.x, E3.y - T3.y);
    }
    __syncthreads();   // tap staging visible (uniform path — compiler-safe)

    // ---- gated npyv Nyquist dot: sign only matters when real[256] < RE_MAX
    // (else |dPhase| <= 1e-6/1e-4 = 0.01 < thr, |dImag| ~1e-6 << bf16 tol).
    float s4x0 = __shfl(S[4].x, 0);
    bool need_nyq = active && (s4x0 < RE_MAX);   // wave-uniform
    if (need_nyq) {
        float s = 0.0f;
        if (lane < 16) {
#pragma unroll 1
            for (int i = 0; i < 8; ++i) {
                int base = 64 * i + lane;
                s = fmarn(exrow[exr_idx(base +  0)], s256f[base +  0], s);
                s = fmarn(exrow[exr_idx(base + 16)], s256f[base + 16], s);
                s = fmarn(exrow[exr_idx(base + 32)], s256f[base + 32], s);
                s = fmarn(exrow[exr_idx(base + 48)], s256f[base + 48], s);
            }
        }
        *nyq_out = -hsum16(s, 0);
    } else {
        *nyq_out = __shfl(S[4].y, 0);   // fast value, within tolerance
    }
    *nyq_used = need_nyq;

    // ---- flag scan: f = lane + 64*j (phase bins f<=256 only)
    unsigned long long flags[5];
    unsigned long long anyf = 0ULL;
#pragma unroll
    for (int j = 0; j < 5; ++j) {
        float2 vv = S[j];
        bool flg = false;
        if (active) {
            if (j == 0 && lane == 0)      flg = fabsf(vv.x) < RE_MAX;   // f=0
            else if (j == 4)              flg = (lane == 0) && (fabsf(vv.x) < RE_MAX); // f=256
            else                          flg = (fabsf(vv.y) < AB_IM && vv.x < RE_MAX) ||
                                                (vv.x * vv.x + vv.y * vv.y < Z2_MIN);
        }
        flags[j] = __ballot(flg);
        anyf |= flags[j];
    }

    if (anyf) {   // per-wave divergent: GOLD_SYNC only (no __syncthreads here)
        // ---- gold window (f32 ops, f64-rounded cos) — R13-verified sequence
        float g_shift = mulrn(addrn(wl - 512.0f, 1.0f), 0.5f);
        float g_lower = floorf(mulrn(511.0f - wl, 0.5f));
        float g_upper = ceilf (mulrn(511.0f + wl, 0.5f));
        float gw[8];
#pragma unroll
        for (int a = 0; a < 8; ++a) {
            int n = 8 * rb + a;
            float base = (float)n - frac;
            float w = 0.0f;
            if (base > g_lower && base < g_upper) {
                float arg = mulrn(TPI_F32, addrn(base, g_shift)) / wl;
                w = 0.5f - mulrn(0.5f, (float)cos((double)arg));
            }
            gw[a] = w;
            exrow[exr_idx(n)] = w;
        }
        GOLD_SYNC();
        // psum: np.sum(axis=0) = strictly sequential over n
        float ps = 0.0f;
        if (lane == 0) {
#pragma unroll 1
            for (int n = 0; n < NF; ++n) ps = addrn(ps, exrow[exr_idx(n)]);
        }
        ps = __shfl(ps, 0);
#pragma unroll
        for (int a = 0; a < 8; ++a) {
            int n = 8 * rb + a;
            float w = gw[a] / ps;                  // np: tap / sum (f32 div)
            if (dopow) w = powf(w, wpow);
            exrow[exr_idx(n)] = mulrn(xr[a], w);   // gold tapered
        }
        GOLD_SYNC();

#pragma unroll
        for (int j = 0; j < 5; ++j) {
            unsigned long long m = flags[j];
            while (m) {
                int src = (int)(__ffsll(m) - 1);
                m &= m - 1;
                int ff = src + 64 * j;
                // lanes 0-15: sin partials; 16-31: cos; FORWARD npyv chain
                float s = 0.0f;
                if (lane < 32) {
                    int L = lane & 15;
                    bool isCos = lane >= 16;
#pragma unroll 1
                    for (int i = 0; i < 8; ++i) {
                        int base = 64 * i + L;
#pragma unroll
                        for (int Bq = 0; Bq < 4; ++Bq) {
                            int n = base + 16 * Bq;
                            double sv, cv;
                            sincos((double)theta32(ff * n), &sv, &cv);
                            s = fmarn(exrow[exr_idx(n)], isCos ? (float)cv : (float)sv, s);
                        }
                    }
                }
                float im = hsum16(s, 0);
                float re = hsum16(s, 16);
                if (lane == src) S[j] = make_float2(re, -im);
            }
        }
        // gold nyq from gold taps
        {
            float s = 0.0f;
            if (lane < 16) {
#pragma unroll 1
                for (int i = 0; i < 8; ++i) {
                    int base = 64 * i + lane;
                    s = fmarn(exrow[exr_idx(base +  0)], s256f[base +  0], s);
                    s = fmarn(exrow[exr_idx(base + 16)], s256f[base + 16], s);
                    s = fmarn(exrow[exr_idx(base + 32)], s256f[base + 32], s);
                    s = fmarn(exrow[exr_idx(base + 48)], s256f[base + 48], s);
                }
            }
            *nyq_out = -hsum16(s, 0);
            *nyq_used = true;
        }
        GOLD_SYNC();
    }
}

// ---------------------------------------------------------------------------
__global__ __launch_bounds__(256) void dstft_fft_kernel(
    const float* __restrict__ x,
    const float* __restrict__ p_stride,
    const float* __restrict__ p_winlen,
    const float* __restrict__ p_winpow,
    const float* __restrict__ s256g,
    float2* __restrict__ scr, size_t scr_cap)
{
    __shared__ float ex[4][NF];
    __shared__ float s256f[NF];

    const int tid  = threadIdx.x;
    const int wv   = tid >> 6;
    const int lane = tid & 63;

    s256f[tid]       = s256g[tid];
    s256f[tid + 256] = s256g[tid + 256];
    __syncthreads();

    float strd = p_stride[0];
    float wl   = fminf(fmaxf(p_winlen[0], (float)(512.0 / 20.0)), 512.0f);
    float wpow = p_winpow[0];
    const bool dopow = (wpow != 1.0f);

    double strd64 = fmin(fmax((double)strd, 0.0), 512.0);

    const int rb = bitrev6(lane);
    const int b  = blockIdx.y;
    const float* xb = x + (size_t)b * LL;

    const int t = blockIdx.x * 4 + wv;
    const bool active = (t < TT);
    double frame64 = strd64 * (double)t;
    int i0 = (int)floor(frame64);
    float frac = (float)(frame64 - floor(frame64));

    float2 S[8];
    float nyq; bool nyq_used;
    dstft_frame_compute(xb, i0, frac, wl, wpow, dopow, s256f, ex[wv],
                        lane, rb, active, S, &nyq, &nyq_used);

    if (active) {
        size_t basez = ((size_t)b * TT + t) * NF;
#pragma unroll
        for (int j = 0; j < 8; ++j) {
            float2 vv = S[j];
            if (j == 0 && lane == 0) vv.y = neg_zero(); // gold: -(+0) = -0.0
            if (j == 4 && lane == 0) vv.y = nyq;        // gold/gated Nyquist
            size_t f = (size_t)(lane + 64 * j);
            if (basez + f < scr_cap) scr[basez + f] = vv;
        }
    }
}

// ---------------------------------------------------------------------------
__global__ __launch_bounds__(256) void dstft_epilogue(
    const float2* __restrict__ scr, size_t scr_cap,
    float* __restrict__ out, size_t oe, int layoutB)
{
    __shared__ float2 tile[32][33];
    const int tx = threadIdx.x;          // 0..31
    const int ty = threadIdx.y;          // 0..7
    const int t0 = blockIdx.x * 32;
    const int f0 = blockIdx.y * 32;
    const int b  = blockIdx.z;

#pragma unroll
    for (int i = 0; i < 4; ++i) {
        int tl = ty + 8 * i;
        int t  = t0 + tl;
        float2 v = make_float2(0.0f, 0.0f);
        size_t si = ((size_t)b * TT + t) * NF + (f0 + tx);
        if (t < TT && si < scr_cap) v = scr[si];
        tile[tl][tx] = v;
    }
    __syncthreads();

    const size_t off_stft  = SPEC_N;
    const size_t off_real  = layoutB ? (SPEC_N + BNT) : (SPEC_N + 2 * BNT);
    const size_t off_imag  = off_real + BNT;
    const size_t off_phase = off_imag + BNT;

#pragma unroll
    for (int i = 0; i < 4; ++i) {
        int fl = ty + 8 * i;
        int f  = f0 + fl;
        int t  = t0 + tx;
        if (t >= TT) continue;
        float2 v = tile[tx][fl];
        size_t o = ((size_t)b * NF + f) * TT + t;
        if (off_real + o < oe) out[off_real + o] = v.x;
        if (off_imag + o < oe) out[off_imag + o] = v.y;
        if (layoutB) {
            if (off_stft + o < oe) out[off_stft + o] = v.x;
        } else {
            size_t os = off_stft + 2 * o;
            if (os + 1 < oe) *reinterpret_cast<float2*>(out + os) = v;
        }
        if (f < FF) {
            size_t o2 = ((size_t)b * FF + f) * TT + t;
            if (o2 < oe) out[o2] = sqrtf(v.x * v.x + v.y * v.y) + 1.1920929e-7f;
            if (off_phase + o2 < oe) out[off_phase + o2] = atan2f(v.y, v.x);
        }
    }
}

// ---------------------------------------------------------------------------
// Fallback (ws too small): fused compute + direct writes.
__global__ __launch_bounds__(256) void dstft_fused(
    const float* __restrict__ x,
    const float* __restrict__ p_stride,
    const float* __restrict__ p_winlen,
    const float* __restrict__ p_winpow,
    float* __restrict__ out, size_t oe, int layoutB)
{
    __shared__ float ex[4][NF];
    __shared__ float s256f[NF];

    const int tid  = threadIdx.x;
    const int wv   = tid >> 6;
    const int lane = tid & 63;

    for (int k = tid; k < NF; k += 256)
        s256f[k] = (float)sin((double)theta32(256 * k));
    __syncthreads();

    float strd = p_stride[0];
    float wl   = fminf(fmaxf(p_winlen[0], (float)(512.0 / 20.0)), 512.0f);
    float wpow = p_winpow[0];
    const bool dopow = (wpow != 1.0f);

    double strd64 = fmin(fmax((double)strd, 0.0), 512.0);
    const int rb = bitrev6(lane);
    const int b  = blockIdx.y;
    const float* xb = x + (size_t)b * LL;

    const int t = blockIdx.x * 4 + wv;
    const bool active = (t < TT);
    double frame64 = strd64 * (double)t;
    int i0 = (int)floor(frame64);
    float frac = (float)(frame64 - floor(frame64));

    float2 S[8];
    float nyq; bool nyq_used;
    dstft_frame_compute(xb, i0, frac, wl, wpow, dopow, s256f, ex[wv],
                        lane, rb, active, S, &nyq, &nyq_used);

    if (active) {
        const size_t off_stft  = SPEC_N;
        const size_t off_real  = layoutB ? (SPEC_N + BNT) : (SPEC_N + 2 * BNT);
        const size_t off_imag  = off_real + BNT;
        const size_t off_phase = off_imag + BNT;
#pragma unroll
        for (int j = 0; j < 8; ++j) {
            float2 vv = S[j];
            if (j == 0 && lane == 0) vv.y = neg_zero();
            if (j == 4 && lane == 0) vv.y = nyq;
            int f = lane + 64 * j;
            size_t o = ((size_t)b * NF + f) * TT + t;
            if (off_real + o < oe) out[off_real + o] = vv.x;
            if (off_imag + o < oe) out[off_imag + o] = vv.y;
            if (layoutB) {
                if (off_stft + o < oe) out[off_stft + o] = vv.x;
            } else {
                size_t os = off_stft + 2 * o;
                if (os + 1 < oe) { out[os] = vv.x; out[os + 1] = vv.y; }
            }
            if (f < FF) {
                size_t o2 = ((size_t)b * FF + f) * TT + t;
                if (o2 < oe) out[o2] = sqrtf(vv.x * vv.x + vv.y * vv.y) + 1.1920929e-7f;
                if (off_phase + o2 < oe) out[off_phase + o2] = atan2f(vv.y, vv.x);
            }
        }
    }
}

// ---------------------------------------------------------------------------
extern "C" void kernel_launch(void* const* d_in, const int* in_sizes, int n_in,
                              void* d_out, int out_size, void* d_ws, size_t ws_size,
                              hipStream_t stream)
{
    const float* x  = (const float*)d_in[0];
    const float* ps = (const float*)d_in[1];
    const float* pw = (const float*)d_in[2];
    const float* pp = (const float*)d_in[3];
    float* out = (float*)d_out;

    const size_t totalA = 2 * SPEC_N + 4 * BNT;   // 40,961,256
    int layoutB = ((size_t)out_size == totalA) ? 0 : 1;   // confirmed: B

    const size_t oe = (size_t)out_size;
    const size_t scrBytes = BNT * sizeof(float2);          // 65.5 MB
    const size_t needWs   = scrBytes + NF * sizeof(float); // + sin table
    const bool use_ws = (d_ws != nullptr) && (ws_size >= needWs);

    if (use_ws) {
        float2* scr   = (float2*)d_ws;
        float*  s256g = (float*)((char*)d_ws + scrBytes);
        dstft_sin256<<<1, NF, 0, stream>>>(s256g);
        dstft_fft_kernel<<<dim3((TT + 3) / 4, BB), 256, 0, stream>>>(
            x, ps, pw, pp, s256g, scr, BNT);
        dstft_epilogue<<<dim3((TT + 31) / 32, NF / 32, BB), dim3(32, 8), 0, stream>>>(
            scr, BNT, out, oe, layoutB);
    } else {
        dstft_fused<<<dim3((TT + 3) / 4, BB), 256, 0, stream>>>(
            x, ps, pw, pp, out, oe, layoutB);
    }
}

// Round 20
// 136.319 us; speedup vs baseline: 1.5253x; 1.0282x over previous
//
#include <hip/hip_runtime.h>
#include <math.h>

#define BB 4
#define LL 512000
#define NF 512
#define TT 3997
#define FF 257
#define TWO_PI 6.28318530717958647692f
#define PI_F 3.14159265358979323846f
// fl32(2*pi) — what the f32 numpy port uses building theta and window args:
#define TPI_F32 6.28318548202514648f

static const size_t SPEC_N = (size_t)BB * FF * TT;   // 4,108,916
static const size_t BNT    = (size_t)BB * NF * TT;   // 8,185,856
// layout B (confirmed r11): spec | stft real-part (BNT) | real | imag | phase

#define AB_IM  3.0e-5f
#define RE_MAX 1.0e-4f
#define Z2_MIN 1.0e-8f

__device__ __forceinline__ float neg_zero() { return __uint_as_float(0x80000000u); }

// Barriered ops: exactly one IEEE-RN rounding each (stops -ffp-contract=fast
// from fusing where numpy has separate ops).
__device__ __forceinline__ float mulrn(float a, float b) { float t = a * b; asm("" : "+v"(t)); return t; }
__device__ __forceinline__ float addrn(float a, float b) { float t = a + b; asm("" : "+v"(t)); return t; }
// Single-rounded fused a*b+c (npyv_muladd on AVX512 = FMA):
__device__ __forceinline__ float fmarn(float a, float b, float c) { float t = fmaf(a, b, c); asm("" : "+v"(t)); return t; }

// np f32 theta: fl32(fl32(2pi)*k)/512  (k = f*n < 2^24 exact; /512 exact)
__device__ __forceinline__ float theta32(int k) {
    return mulrn(TPI_F32, (float)k) / 512.0f;
}

__device__ __forceinline__ int bitrev6(int l) { return (int)(__brev((unsigned)l) >> 26); }

// exrow swizzle: XOR bits5-7 onto bits0-2 — conflict-tamed for both the
// linear writes and the bitrev-slot reads (lane->bank multiset identical).
__device__ __forceinline__ int exr_idx(int n) { return n ^ ((n >> 5) & 7); }

// Intra-wave LDS wait for the per-wave-divergent gold branch ONLY (R13-proven
// pattern; __syncthreads would deadlock there). Rule #18: sched_barrier after.
#define GOLD_SYNC() do { asm volatile("s_waitcnt lgkmcnt(0)" ::: "memory"); \
                         __builtin_amdgcn_sched_barrier(0); } while (0)

// _mm512_reduce_add_ps tree over 16 partials held by lanes base..base+15
__device__ __forceinline__ float hsum16(float s, int base) {
    float q[4];
#pragma unroll
    for (int k = 0; k < 4; ++k) {
        float a = addrn(__shfl(s, base + k),     __shfl(s, base + k + 8));
        float b = addrn(__shfl(s, base + k + 4), __shfl(s, base + k + 12));
        q[k] = addrn(a, b);
    }
    return addrn(addrn(q[0], q[2]), addrn(q[1], q[3]));
}

// ---------------------------------------------------------------------------
__global__ void dstft_sin256(float* __restrict__ s256g)
{
    int n = threadIdx.x;   // 512 threads
    s256g[n] = (float)sin((double)theta32(256 * n));
}

// ---------------------------------------------------------------------------
// One frame: coalesced loads (lane owns n=8*lane..+7) -> window/taps -> LDS ->
// bitrev-slot reads -> register FFT (8x64, f = lane + 64*j) -> gated nyq ->
// gold patches. S[8] out; nyq out. exrow = wave-private LDS (swizzled).
__device__ __forceinline__ void dstft_frame_compute(
    const float* __restrict__ xb, int i0, float frac,
    float wl, float wpow, bool dopow,
    const float* __restrict__ s256f, float* __restrict__ exrow,
    int lane, int rb, bool active, float2* S, float* nyq_out)
{
    // ---- coalesced loads: lane l owns n = 8*l .. 8*l+7
    int nb = i0 + 8 * lane;
    float xr[8];
    if (active && nb >= 0 && nb + 7 < LL && ((i0 & 3) == 0)) {
        float4 p0 = *reinterpret_cast<const float4*>(xb + nb);
        float4 p1 = *reinterpret_cast<const float4*>(xb + nb + 4);
        xr[0] = p0.x; xr[1] = p0.y; xr[2] = p0.z; xr[3] = p0.w;
        xr[4] = p1.x; xr[5] = p1.y; xr[6] = p1.z; xr[7] = p1.w;
    } else {
#pragma unroll
        for (int a = 0; a < 8; ++a) {
            int idx = nb + a;
            xr[a] = (active && idx >= 0 && idx < LL) ? xb[idx] : 0.0f;
        }
    }

    // ---- fast window weights for n = 8*lane + a (HW trig)
    float wwf[8];
    {
        float shift = (wl - 511.0f) * 0.5f;
        float lower = floorf((511.0f - wl) * 0.5f);
        float upper = ceilf ((511.0f + wl) * 0.5f);
        float psum = 0.0f;
#pragma unroll
        for (int a = 0; a < 8; ++a) {
            int n = 8 * lane + a;
            float base = (float)n - frac;
            float w = 0.0f;
            if (base > lower && base < upper)
                w = 0.5f - 0.5f * __cosf(TWO_PI * (base + shift) / wl);
            wwf[a] = w;
            psum += w;
        }
#pragma unroll
        for (int off = 32; off > 0; off >>= 1) psum += __shfl_xor(psum, off);
        float inv = 1.0f / psum;
#pragma unroll
        for (int a = 0; a < 8; ++a) {
            float w = wwf[a] * inv;
            if (dopow) w = powf(w, wpow);
            wwf[a] = w;
        }
    }

    // ---- taps -> LDS (linear ownership, swizzled addresses)
#pragma unroll
    for (int a = 0; a < 8; ++a)
        exrow[exr_idx(8 * lane + a)] = xr[a] * wwf[a];
    __syncthreads();   // taps visible (uniform path — compiler-safe)

    // ---- read this lane's FFT slots n = 8*rb + a from LDS
    float2 z[4];
#pragma unroll
    for (int a = 0; a < 8; ++a) {
        float tapv = exrow[exr_idx(8 * rb + a)];
        if ((a & 1) == 0) z[a >> 1].x = tapv;
        else              z[a >> 1].y = tapv;
    }

    // ---- 4 packed real-pair 64-pt DIT DFTs across lanes
    // stage h=1 (w=1)
#pragma unroll
    for (int c = 0; c < 4; ++c) {
        float px = __shfl_xor(z[c].x, 1), py = __shfl_xor(z[c].y, 1);
        if (lane & 1) { z[c].x = px - z[c].x; z[c].y = py - z[c].y; }
        else          { z[c].x += px;         z[c].y += py; }
    }
    // stages h=2..32 (HW trig twiddle, |arg| <= pi)
#pragma unroll
    for (int s = 1; s < 6; ++s) {
        int h = 1 << s;
        float ws, wc;
        __sincosf(-PI_F * (float)(lane & (h - 1)) / (float)h, &ws, &wc);
#pragma unroll
        for (int c = 0; c < 4; ++c) {
            float px = __shfl_xor(z[c].x, h), py = __shfl_xor(z[c].y, h);
            if (lane & h) {
                float wx = wc * z[c].x - ws * z[c].y;
                float wy = wc * z[c].y + ws * z[c].x;
                z[c].x = px - wx; z[c].y = py - wy;
            } else {
                float wx = wc * px - ws * py;
                float wy = wc * py + ws * px;
                z[c].x += wx; z[c].y += wy;
            }
        }
    }
    // ---- hermitian unpack + twiddle W512^{a*lane} (2-reg chain)
    float2 Bv[8];
    {
        int srcl = (64 - lane) & 63;
#pragma unroll
        for (int c = 0; c < 4; ++c) {
            float rx = __shfl(z[c].x, srcl), ry = __shfl(z[c].y, srcl);
            Bv[2 * c]     = make_float2(0.5f * (z[c].x + rx), 0.5f * (z[c].y - ry));
            Bv[2 * c + 1] = make_float2(0.5f * (z[c].y + ry), -0.5f * (z[c].x - rx));
        }
        float b1s, b1c;
        __sincosf(-(TWO_PI / 512.0f) * (float)lane, &b1s, &b1c);
        float cc = b1c, ss = b1s;
#pragma unroll
        for (int a = 1; a < 8; ++a) {
            float vx = Bv[a].x, vy = Bv[a].y;
            Bv[a] = make_float2(vx * cc - vy * ss, vx * ss + vy * cc);
            if (a < 7) {
                float nc = cc * b1c - ss * b1s;
                float ns = cc * b1s + ss * b1c;
                cc = nc; ss = ns;
            }
        }
    }
    // ---- 8-pt complex DFT over slots: S[j] for f = lane + 64*j
    {
        const float Cq = 0.70710678118654752440f;
        float ex0 = Bv[0].x + Bv[4].x, ey0 = Bv[0].y + Bv[4].y;
        float dx0 = Bv[0].x - Bv[4].x, dy0 = Bv[0].y - Bv[4].y;
        float ex1 = Bv[2].x + Bv[6].x, ey1 = Bv[2].y + Bv[6].y;
        float dx1 = Bv[2].x - Bv[6].x, dy1 = Bv[2].y - Bv[6].y;
        float2 E0 = make_float2(ex0 + ex1, ey0 + ey1);
        float2 E2 = make_float2(ex0 - ex1, ey0 - ey1);
        float2 E1 = make_float2(dx0 + dy1, dy0 - dx1);
        float2 E3 = make_float2(dx0 - dy1, dy0 + dx1);
        float ox0 = Bv[1].x + Bv[5].x, oy0 = Bv[1].y + Bv[5].y;
        float qx0 = Bv[1].x - Bv[5].x, qy0 = Bv[1].y - Bv[5].y;
        float ox1 = Bv[3].x + Bv[7].x, oy1 = Bv[3].y + Bv[7].y;
        float qx1 = Bv[3].x - Bv[7].x, qy1 = Bv[3].y - Bv[7].y;
        float2 O0 = make_float2(ox0 + ox1, oy0 + oy1);
        float2 O2 = make_float2(ox0 - ox1, oy0 - oy1);
        float2 O1 = make_float2(qx0 + qy1, qy0 - qx1);
        float2 O3 = make_float2(qx0 - qy1, qy0 + qx1);
        float2 T0 = O0;
        float2 T1 = make_float2(Cq * (O1.x + O1.y), Cq * (O1.y - O1.x));
        float2 T2 = make_float2(O2.y, -O2.x);
        float2 T3 = make_float2(Cq * (O3.y - O3.x), -Cq * (O3.x + O3.y));
        S[0] = make_float2(E0.x + T0.x, E0.y + T0.y);
        S[4] = make_float2(E0.x - T0.x, E0.y - T0.y);
        S[1] = make_float2(E1.x + T1.x, E1.y + T1.y);
        S[5] = make_float2(E1.x - T1.x, E1.y - T1.y);
        S[2] = make_float2(E2.x + T2.x, E2.y + T2.y);
        S[6] = make_float2(E2.x - T2.x, E2.y - T2.y);
        S[3] = make_float2(E3.x + T3.x, E3.y + T3.y);
        S[7] = make_float2(E3.x - T3.x, E3.y - T3.y);
    }

    // ---- gated npyv Nyquist dot: sign only matters when real[256] < RE_MAX
    // (else |dPhase| <= 1e-6/1e-4 = 0.01 < thr, |dImag| ~1e-6 << bf16 tol).
    // Full unroll preserves the exact FMA chain order; loads pipeline.
    float s4x0 = __shfl(S[4].x, 0);
    bool need_nyq = active && (s4x0 < RE_MAX);   // wave-uniform
    if (need_nyq) {
        float s = 0.0f;
        if (lane < 16) {
#pragma unroll
            for (int i = 0; i < 8; ++i) {
                int base = 64 * i + lane;
                s = fmarn(exrow[exr_idx(base +  0)], s256f[base +  0], s);
                s = fmarn(exrow[exr_idx(base + 16)], s256f[base + 16], s);
                s = fmarn(exrow[exr_idx(base + 32)], s256f[base + 32], s);
                s = fmarn(exrow[exr_idx(base + 48)], s256f[base + 48], s);
            }
        }
        *nyq_out = -hsum16(s, 0);
    } else {
        *nyq_out = __shfl(S[4].y, 0);   // fast value, within tolerance
    }

    // ---- flag scan: f = lane + 64*j (phase bins f<=256 only)
    unsigned long long flags[5];
    unsigned long long anyf = 0ULL;
#pragma unroll
    for (int j = 0; j < 5; ++j) {
        float2 vv = S[j];
        bool flg = false;
        if (active) {
            if (j == 0 && lane == 0)      flg = fabsf(vv.x) < RE_MAX;   // f=0
            else if (j == 4)              flg = (lane == 0) && (fabsf(vv.x) < RE_MAX); // f=256
            else                          flg = (fabsf(vv.y) < AB_IM && vv.x < RE_MAX) ||
                                                (vv.x * vv.x + vv.y * vv.y < Z2_MIN);
        }
        flags[j] = __ballot(flg);
        anyf |= flags[j];
    }

    if (anyf) {   // per-wave divergent: GOLD_SYNC only (no __syncthreads here)
        // ---- gold window (f32 ops, f64-rounded cos) — R13-verified sequence
        float g_shift = mulrn(addrn(wl - 512.0f, 1.0f), 0.5f);
        float g_lower = floorf(mulrn(511.0f - wl, 0.5f));
        float g_upper = ceilf (mulrn(511.0f + wl, 0.5f));
        float gw[8];
#pragma unroll
        for (int a = 0; a < 8; ++a) {
            int n = 8 * lane + a;
            float base = (float)n - frac;
            float w = 0.0f;
            if (base > g_lower && base < g_upper) {
                float arg = mulrn(TPI_F32, addrn(base, g_shift)) / wl;
                w = 0.5f - mulrn(0.5f, (float)cos((double)arg));
            }
            gw[a] = w;
            exrow[exr_idx(n)] = w;
        }
        GOLD_SYNC();
        // psum: np.sum(axis=0) = strictly sequential over n
        float ps = 0.0f;
        if (lane == 0) {
#pragma unroll 1
            for (int n = 0; n < NF; ++n) ps = addrn(ps, exrow[exr_idx(n)]);
        }
        ps = __shfl(ps, 0);
#pragma unroll
        for (int a = 0; a < 8; ++a) {
            int n = 8 * lane + a;
            float w = gw[a] / ps;                  // np: tap / sum (f32 div)
            if (dopow) w = powf(w, wpow);
            exrow[exr_idx(n)] = mulrn(xr[a], w);   // gold tapered
        }
        GOLD_SYNC();

#pragma unroll
        for (int j = 0; j < 5; ++j) {
            unsigned long long m = flags[j];
            while (m) {
                int src = (int)(__ffsll(m) - 1);
                m &= m - 1;
                int ff = src + 64 * j;
                // lanes 0-15: sin partials; 16-31: cos; FORWARD npyv chain
                float s = 0.0f;
                if (lane < 32) {
                    int L = lane & 15;
                    bool isCos = lane >= 16;
#pragma unroll 1
                    for (int i = 0; i < 8; ++i) {
                        int base = 64 * i + L;
#pragma unroll
                        for (int Bq = 0; Bq < 4; ++Bq) {
                            int n = base + 16 * Bq;
                            double sv, cv;
                            sincos((double)theta32(ff * n), &sv, &cv);
                            s = fmarn(exrow[exr_idx(n)], isCos ? (float)cv : (float)sv, s);
                        }
                    }
                }
                float im = hsum16(s, 0);
                float re = hsum16(s, 16);
                if (lane == src) S[j] = make_float2(re, -im);
            }
        }
        // gold nyq from gold taps
        {
            float s = 0.0f;
            if (lane < 16) {
#pragma unroll 1
                for (int i = 0; i < 8; ++i) {
                    int base = 64 * i + lane;
                    s = fmarn(exrow[exr_idx(base +  0)], s256f[base +  0], s);
                    s = fmarn(exrow[exr_idx(base + 16)], s256f[base + 16], s);
                    s = fmarn(exrow[exr_idx(base + 32)], s256f[base + 32], s);
                    s = fmarn(exrow[exr_idx(base + 48)], s256f[base + 48], s);
                }
            }
            *nyq_out = -hsum16(s, 0);
        }
        GOLD_SYNC();
    }
}

// ---------------------------------------------------------------------------
__global__ __launch_bounds__(256) void dstft_fft_kernel(
    const float* __restrict__ x,
    const float* __restrict__ p_stride,
    const float* __restrict__ p_winlen,
    const float* __restrict__ p_winpow,
    const float* __restrict__ s256g,
    float2* __restrict__ scr, size_t scr_cap)
{
    __shared__ float ex[4][NF];
    __shared__ float s256f[NF];

    const int tid  = threadIdx.x;
    const int wv   = tid >> 6;
    const int lane = tid & 63;

    s256f[tid]       = s256g[tid];
    s256f[tid + 256] = s256g[tid + 256];
    __syncthreads();

    float strd = p_stride[0];
    float wl   = fminf(fmaxf(p_winlen[0], (float)(512.0 / 20.0)), 512.0f);
    float wpow = p_winpow[0];
    const bool dopow = (wpow != 1.0f);

    double strd64 = fmin(fmax((double)strd, 0.0), 512.0);

    const int rb = bitrev6(lane);
    const int b  = blockIdx.y;
    const float* xb = x + (size_t)b * LL;

    const int t = blockIdx.x * 4 + wv;
    const bool active = (t < TT);
    double frame64 = strd64 * (double)t;
    int i0 = (int)floor(frame64);
    float frac = (float)(frame64 - floor(frame64));

    float2 S[8];
    float nyq;
    dstft_frame_compute(xb, i0, frac, wl, wpow, dopow, s256f, ex[wv],
                        lane, rb, active, S, &nyq);

    if (active) {
        size_t basez = ((size_t)b * TT + t) * NF;
#pragma unroll
        for (int j = 0; j < 8; ++j) {
            float2 vv = S[j];
            if (j == 0 && lane == 0) vv.y = neg_zero(); // gold: -(+0) = -0.0
            if (j == 4 && lane == 0) vv.y = nyq;        // gold/gated Nyquist
            size_t f = (size_t)(lane + 64 * j);
            if (basez + f < scr_cap) scr[basez + f] = vv;
        }
    }
}

// ---------------------------------------------------------------------------
__global__ __launch_bounds__(256) void dstft_epilogue(
    const float2* __restrict__ scr, size_t scr_cap,
    float* __restrict__ out, size_t oe, int layoutB)
{
    __shared__ float2 tile[32][33];
    const int tx = threadIdx.x;          // 0..31
    const int ty = threadIdx.y;          // 0..7
    const int t0 = blockIdx.x * 32;
    const int f0 = blockIdx.y * 32;
    const int b  = blockIdx.z;

#pragma unroll
    for (int i = 0; i < 4; ++i) {
        int tl = ty + 8 * i;
        int t  = t0 + tl;
        float2 v = make_float2(0.0f, 0.0f);
        size_t si = ((size_t)b * TT + t) * NF + (f0 + tx);
        if (t < TT && si < scr_cap) v = scr[si];
        tile[tl][tx] = v;
    }
    __syncthreads();

    const size_t off_stft  = SPEC_N;
    const size_t off_real  = layoutB ? (SPEC_N + BNT) : (SPEC_N + 2 * BNT);
    const size_t off_imag  = off_real + BNT;
    const size_t off_phase = off_imag + BNT;

#pragma unroll
    for (int i = 0; i < 4; ++i) {
        int fl = ty + 8 * i;
        int f  = f0 + fl;
        int t  = t0 + tx;
        if (t >= TT) continue;
        float2 v = tile[tx][fl];
        size_t o = ((size_t)b * NF + f) * TT + t;
        if (off_real + o < oe) out[off_real + o] = v.x;
        if (off_imag + o < oe) out[off_imag + o] = v.y;
        if (layoutB) {
            if (off_stft + o < oe) out[off_stft + o] = v.x;
        } else {
            size_t os = off_stft + 2 * o;
            if (os + 1 < oe) *reinterpret_cast<float2*>(out + os) = v;
        }
        if (f < FF) {
            size_t o2 = ((size_t)b * FF + f) * TT + t;
            if (o2 < oe) out[o2] = sqrtf(v.x * v.x + v.y * v.y) + 1.1920929e-7f;
            if (off_phase + o2 < oe) out[off_phase + o2] = atan2f(v.y, v.x);
        }
    }
}

// ---------------------------------------------------------------------------
// Fallback (ws too small): fused compute + direct writes.
__global__ __launch_bounds__(256) void dstft_fused(
    const float* __restrict__ x,
    const float* __restrict__ p_stride,
    const float* __restrict__ p_winlen,
    const float* __restrict__ p_winpow,
    float* __restrict__ out, size_t oe, int layoutB)
{
    __shared__ float ex[4][NF];
    __shared__ float s256f[NF];

    const int tid  = threadIdx.x;
    const int wv   = tid >> 6;
    const int lane = tid & 63;

    for (int k = tid; k < NF; k += 256)
        s256f[k] = (float)sin((double)theta32(256 * k));
    __syncthreads();

    float strd = p_stride[0];
    float wl   = fminf(fmaxf(p_winlen[0], (float)(512.0 / 20.0)), 512.0f);
    float wpow = p_winpow[0];
    const bool dopow = (wpow != 1.0f);

    double strd64 = fmin(fmax((double)strd, 0.0), 512.0);
    const int rb = bitrev6(lane);
    const int b  = blockIdx.y;
    const float* xb = x + (size_t)b * LL;

    const int t = blockIdx.x * 4 + wv;
    const bool active = (t < TT);
    double frame64 = strd64 * (double)t;
    int i0 = (int)floor(frame64);
    float frac = (float)(frame64 - floor(frame64));

    float2 S[8];
    float nyq;
    dstft_frame_compute(xb, i0, frac, wl, wpow, dopow, s256f, ex[wv],
                        lane, rb, active, S, &nyq);

    if (active) {
        const size_t off_stft  = SPEC_N;
        const size_t off_real  = layoutB ? (SPEC_N + BNT) : (SPEC_N + 2 * BNT);
        const size_t off_imag  = off_real + BNT;
        const size_t off_phase = off_imag + BNT;
#pragma unroll
        for (int j = 0; j < 8; ++j) {
            float2 vv = S[j];
            if (j == 0 && lane == 0) vv.y = neg_zero();
            if (j == 4 && lane == 0) vv.y = nyq;
            int f = lane + 64 * j;
            size_t o = ((size_t)b * NF + f) * TT + t;
            if (off_real + o < oe) out[off_real + o] = vv.x;
            if (off_imag + o < oe) out[off_imag + o] = vv.y;
            if (layoutB) {
                if (off_stft + o < oe) out[off_stft + o] = vv.x;
            } else {
                size_t os = off_stft + 2 * o;
                if (os + 1 < oe) { out[os] = vv.x; out[os + 1] = vv.y; }
            }
            if (f < FF) {
                size_t o2 = ((size_t)b * FF + f) * TT + t;
                if (o2 < oe) out[o2] = sqrtf(vv.x * vv.x + vv.y * vv.y) + 1.1920929e-7f;
                if (off_phase + o2 < oe) out[off_phase + o2] = atan2f(vv.y, vv.x);
            }
        }
    }
}

// ---------------------------------------------------------------------------
extern "C" void kernel_launch(void* const* d_in, const int* in_sizes, int n_in,
                              void* d_out, int out_size, void* d_ws, size_t ws_size,
                              hipStream_t stream)
{
    const float* x  = (const float*)d_in[0];
    const float* ps = (const float*)d_in[1];
    const float* pw = (const float*)d_in[2];
    const float* pp = (const float*)d_in[3];
    float* out = (float*)d_out;

    const size_t totalA = 2 * SPEC_N + 4 * BNT;   // 40,961,256
    int layoutB = ((size_t)out_size == totalA) ? 0 : 1;   // confirmed: B

    const size_t oe = (size_t)out_size;
    const size_t scrBytes = BNT * sizeof(float2);          // 65.5 MB
    const size_t needWs   = scrBytes + NF * sizeof(float); // + sin table
    const bool use_ws = (d_ws != nullptr) && (ws_size >= needWs);

    if (use_ws) {
        float2* scr   = (float2*)d_ws;
        float*  s256g = (float*)((char*)d_ws + scrBytes);
        dstft_sin256<<<1, NF, 0, stream>>>(s256g);
        dstft_fft_kernel<<<dim3((TT + 3) / 4, BB), 256, 0, stream>>>(
            x, ps, pw, pp, s256g, scr, BNT);
        dstft_epilogue<<<dim3((TT + 31) / 32, NF / 32, BB), dim3(32, 8), 0, stream>>>(
            scr, BNT, out, oe, layoutB);
    } else {
        dstft_fused<<<dim3((TT + 3) / 4, BB), 256, 0, stream>>>(
            x, ps, pw, pp, out, oe, layoutB);
    }
}

// Round 21
// 118.341 us; speedup vs baseline: 1.7571x; 1.1519x over previous
//
#include <hip/hip_runtime.h>
#include <math.h>

#define BB 4
#define LL 512000
#define NF 512
#define TT 3997
#define FF 257
#define TWO_PI 6.28318530717958647692f
#define PI_F 3.14159265358979323846f
// fl32(2*pi) — what the f32 numpy port uses building theta and window args:
#define TPI_F32 6.28318548202514648f

static const size_t SPEC_N = (size_t)BB * FF * TT;   // 4,108,916
static const size_t BNT    = (size_t)BB * NF * TT;   // 8,185,856
// layout B (confirmed r11): spec | stft real-part (BNT) | real | imag | phase

#define AB_IM  3.0e-5f
#define RE_MAX 1.0e-4f
#define Z2_MIN 1.0e-8f

__device__ __forceinline__ float neg_zero() { return __uint_as_float(0x80000000u); }

// Barriered ops: exactly one IEEE-RN rounding each (stops -ffp-contract=fast
// from fusing where numpy has separate ops).
__device__ __forceinline__ float mulrn(float a, float b) { float t = a * b; asm("" : "+v"(t)); return t; }
__device__ __forceinline__ float addrn(float a, float b) { float t = a + b; asm("" : "+v"(t)); return t; }
// Single-rounded fused a*b+c (npyv_muladd on AVX512 = FMA):
__device__ __forceinline__ float fmarn(float a, float b, float c) { float t = fmaf(a, b, c); asm("" : "+v"(t)); return t; }

// np f32 theta: fl32(fl32(2pi)*k)/512  (k = f*n < 2^24 exact; /512 exact)
__device__ __forceinline__ float theta32(int k) {
    return mulrn(TPI_F32, (float)k) / 512.0f;
}

__device__ __forceinline__ int bitrev6(int l) { return (int)(__brev((unsigned)l) >> 26); }

// exrow swizzle: XOR bits5-7 onto bits0-2 — conflict-tamed for both the
// linear writes and the bitrev-slot reads (lane->bank multiset identical).
__device__ __forceinline__ int exr_idx(int n) { return n ^ ((n >> 5) & 7); }

// Intra-wave LDS wait for the per-wave-divergent gold branch ONLY (R13-proven
// pattern; __syncthreads would deadlock there). Rule #18: sched_barrier after.
#define GOLD_SYNC() do { asm volatile("s_waitcnt lgkmcnt(0)" ::: "memory"); \
                         __builtin_amdgcn_sched_barrier(0); } while (0)

// _mm512_reduce_add_ps tree over 16 partials held by lanes base..base+15
__device__ __forceinline__ float hsum16(float s, int base) {
    float q[4];
#pragma unroll
    for (int k = 0; k < 4; ++k) {
        float a = addrn(__shfl(s, base + k),     __shfl(s, base + k + 8));
        float b = addrn(__shfl(s, base + k + 4), __shfl(s, base + k + 12));
        q[k] = addrn(a, b);
    }
    return addrn(addrn(q[0], q[2]), addrn(q[1], q[3]));
}

// ---------------------------------------------------------------------------
// Setup (1 block, 512 threads): s256 table + bit-exact gold window weights at
// frac = 0 (stride is integer in practice). Gold sequence = R13-proven:
// f32 ops, f64-rounded cos, thread-0 sequential psum, f32 division (+pow).
__global__ void dstft_setup(
    const float* __restrict__ p_winlen,
    const float* __restrict__ p_winpow,
    float* __restrict__ s256g, float* __restrict__ wgold)
{
    __shared__ float tmp[NF];
    __shared__ float psh;
    int n = threadIdx.x;   // 512 threads
    s256g[n] = (float)sin((double)theta32(256 * n));

    float wl   = fminf(fmaxf(p_winlen[0], (float)(512.0 / 20.0)), 512.0f);
    float wpow = p_winpow[0];
    float g_shift = mulrn(addrn(wl - 512.0f, 1.0f), 0.5f);
    float g_lower = floorf(mulrn(511.0f - wl, 0.5f));
    float g_upper = ceilf (mulrn(511.0f + wl, 0.5f));
    float base = (float)n;                       // frac = 0
    float w = 0.0f;
    if (base > g_lower && base < g_upper) {
        float arg = mulrn(TPI_F32, addrn(base, g_shift)) / wl;
        w = 0.5f - mulrn(0.5f, (float)cos((double)arg));
    }
    tmp[n] = w;
    __syncthreads();
    if (n == 0) {
        float ps = 0.0f;
#pragma unroll 1
        for (int i = 0; i < NF; ++i) ps = addrn(ps, tmp[i]);
        psh = ps;
    }
    __syncthreads();
    float ww = w / psh;                          // np: tap / sum (f32 div)
    if (wpow != 1.0f) ww = powf(ww, wpow);
    wgold[n] = ww;
}

// ---------------------------------------------------------------------------
// One frame. tableOK: taps = mulrn(x, wgold) are BIT-EXACT gold taps (window
// precomputed); gold branch then needs only the flagged-bin dots. Otherwise
// full R20 path (per-frame fast window + full gold recompute).
__device__ __forceinline__ void dstft_frame_compute(
    const float* __restrict__ xb, int i0, float frac,
    float wl, float wpow, bool dopow, bool tableOK,
    const float* __restrict__ s256f, const float* __restrict__ wlds,
    float* __restrict__ exrow,
    int lane, int rb, bool active, float2* S, float* nyq_out)
{
    // ---- coalesced loads: lane l owns n = 8*l .. 8*l+7
    int nb = i0 + 8 * lane;
    float xr[8];
    if (active && nb >= 0 && nb + 7 < LL && ((i0 & 3) == 0)) {
        float4 p0 = *reinterpret_cast<const float4*>(xb + nb);
        float4 p1 = *reinterpret_cast<const float4*>(xb + nb + 4);
        xr[0] = p0.x; xr[1] = p0.y; xr[2] = p0.z; xr[3] = p0.w;
        xr[4] = p1.x; xr[5] = p1.y; xr[6] = p1.z; xr[7] = p1.w;
    } else {
#pragma unroll
        for (int a = 0; a < 8; ++a) {
            int idx = nb + a;
            xr[a] = (active && idx >= 0 && idx < LL) ? xb[idx] : 0.0f;
        }
    }

    // ---- window weights
    float wwf[8];
    if (tableOK) {
#pragma unroll
        for (int a = 0; a < 8; ++a) wwf[a] = wlds[8 * lane + a];
    } else {
        float shift = (wl - 511.0f) * 0.5f;
        float lower = floorf((511.0f - wl) * 0.5f);
        float upper = ceilf ((511.0f + wl) * 0.5f);
        float psum = 0.0f;
#pragma unroll
        for (int a = 0; a < 8; ++a) {
            int n = 8 * lane + a;
            float base = (float)n - frac;
            float w = 0.0f;
            if (base > lower && base < upper)
                w = 0.5f - 0.5f * __cosf(TWO_PI * (base + shift) / wl);
            wwf[a] = w;
            psum += w;
        }
#pragma unroll
        for (int off = 32; off > 0; off >>= 1) psum += __shfl_xor(psum, off);
        float inv = 1.0f / psum;
#pragma unroll
        for (int a = 0; a < 8; ++a) {
            float w = wwf[a] * inv;
            if (dopow) w = powf(w, wpow);
            wwf[a] = w;
        }
    }

    // ---- taps -> LDS (tableOK: bit-exact gold taps, np's single rounding)
#pragma unroll
    for (int a = 0; a < 8; ++a)
        exrow[exr_idx(8 * lane + a)] = mulrn(xr[a], wwf[a]);
    __syncthreads();   // taps visible (uniform path — compiler-safe)

    // ---- read this lane's FFT slots n = 8*rb + a from LDS
    float2 z[4];
#pragma unroll
    for (int a = 0; a < 8; ++a) {
        float tapv = exrow[exr_idx(8 * rb + a)];
        if ((a & 1) == 0) z[a >> 1].x = tapv;
        else              z[a >> 1].y = tapv;
    }

    // ---- 4 packed real-pair 64-pt DIT DFTs across lanes
#pragma unroll
    for (int c = 0; c < 4; ++c) {
        float px = __shfl_xor(z[c].x, 1), py = __shfl_xor(z[c].y, 1);
        if (lane & 1) { z[c].x = px - z[c].x; z[c].y = py - z[c].y; }
        else          { z[c].x += px;         z[c].y += py; }
    }
#pragma unroll
    for (int s = 1; s < 6; ++s) {
        int h = 1 << s;
        float ws, wc;
        __sincosf(-PI_F * (float)(lane & (h - 1)) / (float)h, &ws, &wc);
#pragma unroll
        for (int c = 0; c < 4; ++c) {
            float px = __shfl_xor(z[c].x, h), py = __shfl_xor(z[c].y, h);
            if (lane & h) {
                float wx = wc * z[c].x - ws * z[c].y;
                float wy = wc * z[c].y + ws * z[c].x;
                z[c].x = px - wx; z[c].y = py - wy;
            } else {
                float wx = wc * px - ws * py;
                float wy = wc * py + ws * px;
                z[c].x += wx; z[c].y += wy;
            }
        }
    }
    // ---- hermitian unpack + twiddle W512^{a*lane} (2-reg chain)
    float2 Bv[8];
    {
        int srcl = (64 - lane) & 63;
#pragma unroll
        for (int c = 0; c < 4; ++c) {
            float rx = __shfl(z[c].x, srcl), ry = __shfl(z[c].y, srcl);
            Bv[2 * c]     = make_float2(0.5f * (z[c].x + rx), 0.5f * (z[c].y - ry));
            Bv[2 * c + 1] = make_float2(0.5f * (z[c].y + ry), -0.5f * (z[c].x - rx));
        }
        float b1s, b1c;
        __sincosf(-(TWO_PI / 512.0f) * (float)lane, &b1s, &b1c);
        float cc = b1c, ss = b1s;
#pragma unroll
        for (int a = 1; a < 8; ++a) {
            float vx = Bv[a].x, vy = Bv[a].y;
            Bv[a] = make_float2(vx * cc - vy * ss, vx * ss + vy * cc);
            if (a < 7) {
                float nc = cc * b1c - ss * b1s;
                float ns = cc * b1s + ss * b1c;
                cc = nc; ss = ns;
            }
        }
    }
    // ---- 8-pt complex DFT over slots: S[j] for f = lane + 64*j
    {
        const float Cq = 0.70710678118654752440f;
        float ex0 = Bv[0].x + Bv[4].x, ey0 = Bv[0].y + Bv[4].y;
        float dx0 = Bv[0].x - Bv[4].x, dy0 = Bv[0].y - Bv[4].y;
        float ex1 = Bv[2].x + Bv[6].x, ey1 = Bv[2].y + Bv[6].y;
        float dx1 = Bv[2].x - Bv[6].x, dy1 = Bv[2].y - Bv[6].y;
        float2 E0 = make_float2(ex0 + ex1, ey0 + ey1);
        float2 E2 = make_float2(ex0 - ex1, ey0 - ey1);
        float2 E1 = make_float2(dx0 + dy1, dy0 - dx1);
        float2 E3 = make_float2(dx0 - dy1, dy0 + dx1);
        float ox0 = Bv[1].x + Bv[5].x, oy0 = Bv[1].y + Bv[5].y;
        float qx0 = Bv[1].x - Bv[5].x, qy0 = Bv[1].y - Bv[5].y;
        float ox1 = Bv[3].x + Bv[7].x, oy1 = Bv[3].y + Bv[7].y;
        float qx1 = Bv[3].x - Bv[7].x, qy1 = Bv[3].y - Bv[7].y;
        float2 O0 = make_float2(ox0 + ox1, oy0 + oy1);
        float2 O2 = make_float2(ox0 - ox1, oy0 - oy1);
        float2 O1 = make_float2(qx0 + qy1, qy0 - qx1);
        float2 O3 = make_float2(qx0 - qy1, qy0 + qx1);
        float2 T0 = O0;
        float2 T1 = make_float2(Cq * (O1.x + O1.y), Cq * (O1.y - O1.x));
        float2 T2 = make_float2(O2.y, -O2.x);
        float2 T3 = make_float2(Cq * (O3.y - O3.x), -Cq * (O3.x + O3.y));
        S[0] = make_float2(E0.x + T0.x, E0.y + T0.y);
        S[4] = make_float2(E0.x - T0.x, E0.y - T0.y);
        S[1] = make_float2(E1.x + T1.x, E1.y + T1.y);
        S[5] = make_float2(E1.x - T1.x, E1.y - T1.y);
        S[2] = make_float2(E2.x + T2.x, E2.y + T2.y);
        S[6] = make_float2(E2.x - T2.x, E2.y - T2.y);
        S[3] = make_float2(E3.x + T3.x, E3.y + T3.y);
        S[7] = make_float2(E3.x - T3.x, E3.y - T3.y);
    }

    // ---- gated npyv Nyquist dot (taps in exrow are gold when tableOK)
    float s4x0 = __shfl(S[4].x, 0);
    bool need_nyq = active && (s4x0 < RE_MAX);   // wave-uniform
    if (need_nyq) {
        float s = 0.0f;
        if (lane < 16) {
#pragma unroll
            for (int i = 0; i < 8; ++i) {
                int base = 64 * i + lane;
                s = fmarn(exrow[exr_idx(base +  0)], s256f[base +  0], s);
                s = fmarn(exrow[exr_idx(base + 16)], s256f[base + 16], s);
                s = fmarn(exrow[exr_idx(base + 32)], s256f[base + 32], s);
                s = fmarn(exrow[exr_idx(base + 48)], s256f[base + 48], s);
            }
        }
        *nyq_out = -hsum16(s, 0);
    } else {
        *nyq_out = __shfl(S[4].y, 0);   // fast value, within tolerance
    }

    // ---- flag scan: f = lane + 64*j (phase bins f<=256 only)
    unsigned long long flags[5];
    unsigned long long anyf = 0ULL;
#pragma unroll
    for (int j = 0; j < 5; ++j) {
        float2 vv = S[j];
        bool flg = false;
        if (active) {
            if (j == 0 && lane == 0)      flg = fabsf(vv.x) < RE_MAX;   // f=0
            else if (j == 4)              flg = (lane == 0) && (fabsf(vv.x) < RE_MAX); // f=256
            else                          flg = (fabsf(vv.y) < AB_IM && vv.x < RE_MAX) ||
                                                (vv.x * vv.x + vv.y * vv.y < Z2_MIN);
        }
        flags[j] = __ballot(flg);
        anyf |= flags[j];
    }

    if (anyf) {   // per-wave divergent: GOLD_SYNC only (no __syncthreads here)
        if (!tableOK) {
            // full gold window + sequential psum + gold taps (R13 sequence)
            float g_shift = mulrn(addrn(wl - 512.0f, 1.0f), 0.5f);
            float g_lower = floorf(mulrn(511.0f - wl, 0.5f));
            float g_upper = ceilf (mulrn(511.0f + wl, 0.5f));
            float gw[8];
#pragma unroll
            for (int a = 0; a < 8; ++a) {
                int n = 8 * lane + a;
                float base = (float)n - frac;
                float w = 0.0f;
                if (base > g_lower && base < g_upper) {
                    float arg = mulrn(TPI_F32, addrn(base, g_shift)) / wl;
                    w = 0.5f - mulrn(0.5f, (float)cos((double)arg));
                }
                gw[a] = w;
                exrow[exr_idx(n)] = w;
            }
            GOLD_SYNC();
            float ps = 0.0f;
            if (lane == 0) {
#pragma unroll 1
                for (int n = 0; n < NF; ++n) ps = addrn(ps, exrow[exr_idx(n)]);
            }
            ps = __shfl(ps, 0);
#pragma unroll
            for (int a = 0; a < 8; ++a) {
                int n = 8 * lane + a;
                float w = gw[a] / ps;
                if (dopow) w = powf(w, wpow);
                exrow[exr_idx(n)] = mulrn(xr[a], w);
            }
            GOLD_SYNC();
        }
        // taps in exrow are gold now (either path). Flagged-bin npyv dots:
#pragma unroll
        for (int j = 0; j < 5; ++j) {
            unsigned long long m = flags[j];
            while (m) {
                int src = (int)(__ffsll(m) - 1);
                m &= m - 1;
                int ff = src + 64 * j;
                float s = 0.0f;
                if (lane < 32) {
                    int L = lane & 15;
                    bool isCos = lane >= 16;
#pragma unroll 1
                    for (int i = 0; i < 8; ++i) {
                        int base = 64 * i + L;
#pragma unroll
                        for (int Bq = 0; Bq < 4; ++Bq) {
                            int n = base + 16 * Bq;
                            double sv, cv;
                            sincos((double)theta32(ff * n), &sv, &cv);
                            s = fmarn(exrow[exr_idx(n)], isCos ? (float)cv : (float)sv, s);
                        }
                    }
                }
                float im = hsum16(s, 0);
                float re = hsum16(s, 16);
                if (lane == src) S[j] = make_float2(re, -im);
            }
        }
        // gold nyq from gold taps (recompute needed only when taps changed)
        if (!tableOK) {
            float s = 0.0f;
            if (lane < 16) {
#pragma unroll 1
                for (int i = 0; i < 8; ++i) {
                    int base = 64 * i + lane;
                    s = fmarn(exrow[exr_idx(base +  0)], s256f[base +  0], s);
                    s = fmarn(exrow[exr_idx(base + 16)], s256f[base + 16], s);
                    s = fmarn(exrow[exr_idx(base + 32)], s256f[base + 32], s);
                    s = fmarn(exrow[exr_idx(base + 48)], s256f[base + 48], s);
                }
            }
            *nyq_out = -hsum16(s, 0);
            GOLD_SYNC();
        } else if (!need_nyq) {
            // taps are gold but the fast nyq was skipped; bin 256 may be
            // flagged only via lane0/j4 which requires |re|<RE_MAX — that
            // implies need_nyq was true. So nothing to do here.
        }
    }
}

// ---------------------------------------------------------------------------
__global__ __launch_bounds__(256) void dstft_fft_kernel(
    const float* __restrict__ x,
    const float* __restrict__ p_stride,
    const float* __restrict__ p_winlen,
    const float* __restrict__ p_winpow,
    const float* __restrict__ s256g,
    const float* __restrict__ wgold,
    float2* __restrict__ scr, size_t scr_cap)
{
    __shared__ float ex[4][NF];
    __shared__ float s256f[NF];
    __shared__ float wlds[NF];

    const int tid  = threadIdx.x;
    const int wv   = tid >> 6;
    const int lane = tid & 63;

    s256f[tid]       = s256g[tid];
    s256f[tid + 256] = s256g[tid + 256];
    wlds[tid]        = wgold[tid];
    wlds[tid + 256]  = wgold[tid + 256];
    __syncthreads();

    float strd = p_stride[0];
    float wl   = fminf(fmaxf(p_winlen[0], (float)(512.0 / 20.0)), 512.0f);
    float wpow = p_winpow[0];
    const bool dopow = (wpow != 1.0f);

    double strd64 = fmin(fmax((double)strd, 0.0), 512.0);

    const int rb = bitrev6(lane);
    const int b  = blockIdx.y;
    const float* xb = x + (size_t)b * LL;

    const int t = blockIdx.x * 4 + wv;
    const bool active = (t < TT);
    double frame64 = strd64 * (double)t;
    int i0 = (int)floor(frame64);
    double frac64 = frame64 - floor(frame64);
    float frac = (float)frac64;
    const bool tableOK = (frac64 == 0.0);

    float2 S[8];
    float nyq;
    dstft_frame_compute(xb, i0, frac, wl, wpow, dopow, tableOK,
                        s256f, wlds, ex[wv], lane, rb, active, S, &nyq);

    if (active) {
        size_t basez = ((size_t)b * TT + t) * NF;
#pragma unroll
        for (int j = 0; j < 8; ++j) {
            float2 vv = S[j];
            if (j == 0 && lane == 0) vv.y = neg_zero(); // gold: -(+0) = -0.0
            if (j == 4 && lane == 0) vv.y = nyq;        // gold/gated Nyquist
            size_t f = (size_t)(lane + 64 * j);
            if (basez + f < scr_cap) scr[basez + f] = vv;
        }
    }
}

// ---------------------------------------------------------------------------
__global__ __launch_bounds__(256) void dstft_epilogue(
    const float2* __restrict__ scr, size_t scr_cap,
    float* __restrict__ out, size_t oe, int layoutB)
{
    __shared__ float2 tile[32][33];
    const int tx = threadIdx.x;          // 0..31
    const int ty = threadIdx.y;          // 0..7
    const int t0 = blockIdx.x * 32;
    const int f0 = blockIdx.y * 32;
    const int b  = blockIdx.z;

#pragma unroll
    for (int i = 0; i < 4; ++i) {
        int tl = ty + 8 * i;
        int t  = t0 + tl;
        float2 v = make_float2(0.0f, 0.0f);
        size_t si = ((size_t)b * TT + t) * NF + (f0 + tx);
        if (t < TT && si < scr_cap) v = scr[si];
        tile[tl][tx] = v;
    }
    __syncthreads();

    const size_t off_stft  = SPEC_N;
    const size_t off_real  = layoutB ? (SPEC_N + BNT) : (SPEC_N + 2 * BNT);
    const size_t off_imag  = off_real + BNT;
    const size_t off_phase = off_imag + BNT;

#pragma unroll
    for (int i = 0; i < 4; ++i) {
        int fl = ty + 8 * i;
        int f  = f0 + fl;
        int t  = t0 + tx;
        if (t >= TT) continue;
        float2 v = tile[tx][fl];
        size_t o = ((size_t)b * NF + f) * TT + t;
        if (off_real + o < oe) out[off_real + o] = v.x;
        if (off_imag + o < oe) out[off_imag + o] = v.y;
        if (layoutB) {
            if (off_stft + o < oe) out[off_stft + o] = v.x;
        } else {
            size_t os = off_stft + 2 * o;
            if (os + 1 < oe) *reinterpret_cast<float2*>(out + os) = v;
        }
        if (f < FF) {
            size_t o2 = ((size_t)b * FF + f) * TT + t;
            if (o2 < oe) out[o2] = sqrtf(v.x * v.x + v.y * v.y) + 1.1920929e-7f;
            if (off_phase + o2 < oe) out[off_phase + o2] = atan2f(v.y, v.x);
        }
    }
}

// ---------------------------------------------------------------------------
// Fallback (ws too small): fused compute + direct writes (no table).
__global__ __launch_bounds__(256) void dstft_fused(
    const float* __restrict__ x,
    const float* __restrict__ p_stride,
    const float* __restrict__ p_winlen,
    const float* __restrict__ p_winpow,
    float* __restrict__ out, size_t oe, int layoutB)
{
    __shared__ float ex[4][NF];
    __shared__ float s256f[NF];

    const int tid  = threadIdx.x;
    const int wv   = tid >> 6;
    const int lane = tid & 63;

    for (int k = tid; k < NF; k += 256)
        s256f[k] = (float)sin((double)theta32(256 * k));
    __syncthreads();

    float strd = p_stride[0];
    float wl   = fminf(fmaxf(p_winlen[0], (float)(512.0 / 20.0)), 512.0f);
    float wpow = p_winpow[0];
    const bool dopow = (wpow != 1.0f);

    double strd64 = fmin(fmax((double)strd, 0.0), 512.0);
    const int rb = bitrev6(lane);
    const int b  = blockIdx.y;
    const float* xb = x + (size_t)b * LL;

    const int t = blockIdx.x * 4 + wv;
    const bool active = (t < TT);
    double frame64 = strd64 * (double)t;
    int i0 = (int)floor(frame64);
    float frac = (float)(frame64 - floor(frame64));

    float2 S[8];
    float nyq;
    dstft_frame_compute(xb, i0, frac, wl, wpow, dopow, false,
                        s256f, nullptr, ex[wv], lane, rb, active, S, &nyq);

    if (active) {
        const size_t off_stft  = SPEC_N;
        const size_t off_real  = layoutB ? (SPEC_N + BNT) : (SPEC_N + 2 * BNT);
        const size_t off_imag  = off_real + BNT;
        const size_t off_phase = off_imag + BNT;
#pragma unroll
        for (int j = 0; j < 8; ++j) {
            float2 vv = S[j];
            if (j == 0 && lane == 0) vv.y = neg_zero();
            if (j == 4 && lane == 0) vv.y = nyq;
            int f = lane + 64 * j;
            size_t o = ((size_t)b * NF + f) * TT + t;
            if (off_real + o < oe) out[off_real + o] = vv.x;
            if (off_imag + o < oe) out[off_imag + o] = vv.y;
            if (layoutB) {
                if (off_stft + o < oe) out[off_stft + o] = vv.x;
            } else {
                size_t os = off_stft + 2 * o;
                if (os + 1 < oe) { out[os] = vv.x; out[os + 1] = vv.y; }
            }
            if (f < FF) {
                size_t o2 = ((size_t)b * FF + f) * TT + t;
                if (o2 < oe) out[o2] = sqrtf(vv.x * vv.x + vv.y * vv.y) + 1.1920929e-7f;
                if (off_phase + o2 < oe) out[off_phase + o2] = atan2f(vv.y, vv.x);
            }
        }
    }
}

// ---------------------------------------------------------------------------
extern "C" void kernel_launch(void* const* d_in, const int* in_sizes, int n_in,
                              void* d_out, int out_size, void* d_ws, size_t ws_size,
                              hipStream_t stream)
{
    const float* x  = (const float*)d_in[0];
    const float* ps = (const float*)d_in[1];
    const float* pw = (const float*)d_in[2];
    const float* pp = (const float*)d_in[3];
    float* out = (float*)d_out;

    const size_t totalA = 2 * SPEC_N + 4 * BNT;   // 40,961,256
    int layoutB = ((size_t)out_size == totalA) ? 0 : 1;   // confirmed: B

    const size_t oe = (size_t)out_size;
    const size_t scrBytes = BNT * sizeof(float2);              // 65.5 MB
    const size_t needWs   = scrBytes + 2 * NF * sizeof(float); // + tables
    const bool use_ws = (d_ws != nullptr) && (ws_size >= needWs);

    if (use_ws) {
        float2* scr   = (float2*)d_ws;
        float*  s256g = (float*)((char*)d_ws + scrBytes);
        float*  wgold = s256g + NF;
        dstft_setup<<<1, NF, 0, stream>>>(pw, pp, s256g, wgold);
        dstft_fft_kernel<<<dim3((TT + 3) / 4, BB), 256, 0, stream>>>(
            x, ps, pw, pp, s256g, wgold, scr, BNT);
        dstft_epilogue<<<dim3((TT + 31) / 32, NF / 32, BB), dim3(32, 8), 0, stream>>>(
            scr, BNT, out, oe, layoutB);
    } else {
        dstft_fused<<<dim3((TT + 3) / 4, BB), 256, 0, stream>>>(
            x, ps, pw, pp, out, oe, layoutB);
    }
}